// Round 1
// baseline (889.644 us; speedup 1.0000x reference)
//
#include <hip/hip_runtime.h>

#define NG 20000   // NUM_GENES
#define BB 8       // batch
#define FD 128     // feature dim

// ---------------- small setup kernels ----------------

__global__ void k_init(float* deg, int* cursor, float* s_acc, int N) {
    int i = blockIdx.x * blockDim.x + threadIdx.x;
    if (i < N) { deg[i] = 1.0f; cursor[i] = 0; }
    if (i < BB * FD) s_acc[i] = 0.0f;
}

__global__ void k_count(const int* __restrict__ dst, float* deg, int E) {
    int e = blockIdx.x * blockDim.x + threadIdx.x;
    if (e < E) atomicAdd(&deg[dst[e]], 1.0f);
}

__global__ void k_node(const float* __restrict__ deg, float* dinv, float* cval,
                       int* indeg, int N) {
    int i = blockIdx.x * blockDim.x + threadIdx.x;
    if (i < N) {
        float d = deg[i];
        dinv[i]  = rsqrtf(d);
        cval[i]  = 1.0f / d;          // self-loop contribution to c[i]
        indeg[i] = (int)d - 1;        // in-degree excluding self loop
    }
}

// exclusive scan of indeg -> offs (2-level, blockDim must be 256)
__global__ void k_scan1(const int* __restrict__ indeg, int* offs, int* bsums, int N) {
    __shared__ int sd[256];
    int t = threadIdx.x, idx = blockIdx.x * 256 + t;
    int v = (idx < N) ? indeg[idx] : 0;
    sd[t] = v; __syncthreads();
    for (int o = 1; o < 256; o <<= 1) {
        int x = (t >= o) ? sd[t - o] : 0;
        __syncthreads();
        sd[t] += x;
        __syncthreads();
    }
    if (idx < N) offs[idx] = sd[t] - v;
    if (t == 255) bsums[blockIdx.x] = sd[255];
}

__global__ void k_scan2(int* bsums, int nb) {
    __shared__ int sd[256];
    int t = threadIdx.x;
    int v = (t < nb) ? bsums[t] : 0;
    sd[t] = v; __syncthreads();
    for (int o = 1; o < 256; o <<= 1) {
        int x = (t >= o) ? sd[t - o] : 0;
        __syncthreads();
        sd[t] += x;
        __syncthreads();
    }
    if (t < nb) bsums[t] = sd[t] - v;   // exclusive
}

__global__ void k_scan3(int* offs, const int* __restrict__ bsums, int N) {
    int i = blockIdx.x * blockDim.x + threadIdx.x;
    if (i < N) offs[i] += bsums[blockIdx.x];  // blockDim==256 so i>>8==blockIdx
}

// build CSR by dst; also accumulate c[src] += norm. csr entry: {gene_row(src), norm bits}
__global__ void k_fill(const int* __restrict__ src, const int* __restrict__ dst,
                       const int* __restrict__ gid, const float* __restrict__ dinv,
                       float* cval, const int* __restrict__ offs, int* cursor,
                       int2* csr, int E) {
    int e = blockIdx.x * blockDim.x + threadIdx.x;
    if (e >= E) return;
    int s = src[e], d = dst[e];
    float nrm = dinv[s] * dinv[d];
    atomicAdd(&cval[s], nrm);
    int pos = atomicAdd(&cursor[d], 1);
    csr[offs[d] + pos] = make_int2(gid[s], __float_as_int(nrm));
}

// ---------------- aggregation: aggU[i][b][f] = sum_in-edges norm * gene_emb[b, gid[src], f] ----------------
// block = 512 threads = 8 waves; wave w handles batch b=w; lane holds float2 of features.
__global__ void k_agg(const float* __restrict__ gene, const int* __restrict__ gid,
                      const float* __restrict__ deg, const int2* __restrict__ csr,
                      const int* __restrict__ offs, const int* __restrict__ indeg,
                      float* __restrict__ aggU, int N) {
    int b    = threadIdx.x >> 6;
    int lane = threadIdx.x & 63;
    const float* gbase = gene + (size_t)b * NG * FD + lane * 2;
    for (int i = blockIdx.x; i < N; i += gridDim.x) {
        int start = offs[i], cnt = indeg[i];
        float w = 1.0f / deg[i];                      // dinv^2 (self loop)
        const float2 vs = *(const float2*)(gbase + (size_t)gid[i] * FD);
        float ax = w * vs.x, ay = w * vs.y;
        int e = start, end = start + cnt;
        for (; e + 1 < end; e += 2) {                 // 2-wide for MLP
            int2 c0 = csr[e], c1 = csr[e + 1];
            float n0 = __int_as_float(c0.y), n1 = __int_as_float(c1.y);
            float2 v0 = *(const float2*)(gbase + (size_t)c0.x * FD);
            float2 v1 = *(const float2*)(gbase + (size_t)c1.x * FD);
            ax += n0 * v0.x; ay += n0 * v0.y;
            ax += n1 * v1.x; ay += n1 * v1.y;
        }
        if (e < end) {
            int2 c0 = csr[e];
            float n0 = __int_as_float(c0.y);
            float2 v0 = *(const float2*)(gbase + (size_t)c0.x * FD);
            ax += n0 * v0.x; ay += n0 * v0.y;
        }
        *(float2*)(aggU + (size_t)i * (BB * FD) + b * FD + lane * 2) = make_float2(ax, ay);
    }
}

// ---------------- GEMM + relu + c-weighted reduce into s_acc[b][j] ----------------
// block 512: 16 nodes/group; thread = (ng 0..15, jg 0..31) computes 8 batches x 4 cols.
__global__ __launch_bounds__(512, 1)
void k_gemm(const float* __restrict__ aggU, const float* __restrict__ W1,
            const float* __restrict__ b1, const float* __restrict__ cval,
            float* __restrict__ s_acc, int N) {
    __shared__ float W1s[128 * 128];        // 64 KB
    __shared__ float rowT[16 * 128 * 8];    // 64 KB  [node][k][b]
    __shared__ float b1s[128];
    int t = threadIdx.x;
    for (int idx = t; idx < 16384; idx += 512) W1s[idx] = W1[idx];
    if (t < 128) b1s[t] = b1[t];

    int jg = t & 31, j0 = jg * 4, ng = t >> 5;
    float4 sac[8];
#pragma unroll
    for (int b = 0; b < 8; b++) sac[b] = make_float4(0.f, 0.f, 0.f, 0.f);

    int ngroups = (N + 15) >> 4;
    for (int g = blockIdx.x; g < ngroups; g += gridDim.x) {
        __syncthreads();   // protect rowT (prev iter readers done)
        // stage 16 nodes, transposed to [node][k][b]; contiguous LDS writes
#pragma unroll
        for (int rep = 0; rep < 8; rep++) {
            int flat = rep * 2048 + t * 4;   // float index into rowT
            int nk = flat >> 3;              // n*128 + k
            int b0 = flat & 7;               // 0 or 4
            int n  = nk >> 7, k = nk & 127;
            int node = (g << 4) + n;
            float4 v = make_float4(0.f, 0.f, 0.f, 0.f);
            if (node < N) {
                const float* gp = aggU + (size_t)node * 1024 + k;
                v.x = gp[(b0 + 0) * 128];
                v.y = gp[(b0 + 1) * 128];
                v.z = gp[(b0 + 2) * 128];
                v.w = gp[(b0 + 3) * 128];
            }
            *(float4*)&rowT[flat] = v;
        }
        __syncthreads();

        float4 acc[8];
#pragma unroll
        for (int b = 0; b < 8; b++) acc[b] = make_float4(0.f, 0.f, 0.f, 0.f);
        const float* rbase = &rowT[ng * 128 * 8];
#pragma unroll 4
        for (int k = 0; k < 128; k++) {
            float4 w  = *(const float4*)&W1s[k * 128 + j0];
            float4 ra = *(const float4*)&rbase[k * 8];
            float4 rb = *(const float4*)&rbase[k * 8 + 4];
            acc[0].x += ra.x * w.x; acc[0].y += ra.x * w.y; acc[0].z += ra.x * w.z; acc[0].w += ra.x * w.w;
            acc[1].x += ra.y * w.x; acc[1].y += ra.y * w.y; acc[1].z += ra.y * w.z; acc[1].w += ra.y * w.w;
            acc[2].x += ra.z * w.x; acc[2].y += ra.z * w.y; acc[2].z += ra.z * w.z; acc[2].w += ra.z * w.w;
            acc[3].x += ra.w * w.x; acc[3].y += ra.w * w.y; acc[3].z += ra.w * w.z; acc[3].w += ra.w * w.w;
            acc[4].x += rb.x * w.x; acc[4].y += rb.x * w.y; acc[4].z += rb.x * w.z; acc[4].w += rb.x * w.w;
            acc[5].x += rb.y * w.x; acc[5].y += rb.y * w.y; acc[5].z += rb.y * w.z; acc[5].w += rb.y * w.w;
            acc[6].x += rb.z * w.x; acc[6].y += rb.z * w.y; acc[6].z += rb.z * w.z; acc[6].w += rb.z * w.w;
            acc[7].x += rb.w * w.x; acc[7].y += rb.w * w.y; acc[7].z += rb.w * w.z; acc[7].w += rb.w * w.w;
        }
        int node = (g << 4) + ng;
        float cv = (node < N) ? cval[node] : 0.0f;
#pragma unroll
        for (int b = 0; b < 8; b++) {
            sac[b].x += cv * fmaxf(acc[b].x + b1s[j0 + 0], 0.0f);
            sac[b].y += cv * fmaxf(acc[b].y + b1s[j0 + 1], 0.0f);
            sac[b].z += cv * fmaxf(acc[b].z + b1s[j0 + 2], 0.0f);
            sac[b].w += cv * fmaxf(acc[b].w + b1s[j0 + 3], 0.0f);
        }
    }

    // block reduce into LDS (reuse rowT), then one atomic pass to global
    __syncthreads();
    float* s_lds = rowT;
    for (int idx = t; idx < 1024; idx += 512) s_lds[idx] = 0.0f;
    __syncthreads();
#pragma unroll
    for (int b = 0; b < 8; b++) {
        atomicAdd(&s_lds[b * 128 + j0 + 0], sac[b].x);
        atomicAdd(&s_lds[b * 128 + j0 + 1], sac[b].y);
        atomicAdd(&s_lds[b * 128 + j0 + 2], sac[b].z);
        atomicAdd(&s_lds[b * 128 + j0 + 3], sac[b].w);
    }
    __syncthreads();
    for (int idx = t; idx < 1024; idx += 512) atomicAdd(&s_acc[idx], s_lds[idx]);
}

// out[b][j] = (s[b] @ W2)[j] / N + b2[j]   (tiny: 8x128x128)
__global__ void k_final(const float* __restrict__ s_acc, const float* __restrict__ W2,
                        const float* __restrict__ b2, float* __restrict__ out, float invN) {
    __shared__ float ss[1024];
    int t = threadIdx.x;  // 128 threads
    for (int idx = t; idx < 1024; idx += 128) ss[idx] = s_acc[idx];
    __syncthreads();
    float acc[8];
#pragma unroll
    for (int b = 0; b < 8; b++) acc[b] = 0.f;
    for (int k = 0; k < 128; k++) {
        float w = W2[k * 128 + t];
#pragma unroll
        for (int b = 0; b < 8; b++) acc[b] += ss[b * 128 + k] * w;
    }
    float bb = b2[t];
#pragma unroll
    for (int b = 0; b < 8; b++) out[b * 128 + t] = acc[b] * invN + bb;
}

// ---------------- launcher ----------------

extern "C" void kernel_launch(void* const* d_in, const int* in_sizes, int n_in,
                              void* d_out, int out_size, void* d_ws, size_t ws_size,
                              hipStream_t stream) {
    const float* gene = (const float*)d_in[0];
    const float* W1   = (const float*)d_in[1];
    const float* b1   = (const float*)d_in[2];
    const float* W2   = (const float*)d_in[3];
    const float* b2   = (const float*)d_in[4];
    const int*   gid  = (const int*)d_in[5];
    const int*   eidx = (const int*)d_in[6];
    int N = in_sizes[5];
    int E = in_sizes[6] / 2;
    const int* src = eidx;
    const int* dst = eidx + E;
    float* out = (float*)d_out;

    char* p = (char*)d_ws;
    auto alloc = [&](size_t bytes) -> char* {
        char* r = p; p += (bytes + 255) & ~(size_t)255; return r;
    };
    float* deg    = (float*)alloc((size_t)N * 4);
    float* dinv   = (float*)alloc((size_t)N * 4);
    float* cval   = (float*)alloc((size_t)N * 4);
    int*   indeg  = (int*)  alloc((size_t)N * 4);
    int*   offs   = (int*)  alloc((size_t)N * 4);
    int*   cursor = (int*)  alloc((size_t)N * 4);
    int*   bsums  = (int*)  alloc(256 * 4);
    int2*  csr    = (int2*) alloc((size_t)E * 8);
    float* s_acc  = (float*)alloc(1024 * 4);
    float* aggU   = (float*)alloc((size_t)N * 1024 * 4);

    int nb = (N + 255) / 256;   // 196 (must be <= 256 for scan2)
    int eb = (E + 255) / 256;

    k_init <<<nb, 256, 0, stream>>>(deg, cursor, s_acc, N);
    k_count<<<eb, 256, 0, stream>>>(dst, deg, E);
    k_node <<<nb, 256, 0, stream>>>(deg, dinv, cval, indeg, N);
    k_scan1<<<nb, 256, 0, stream>>>(indeg, offs, bsums, N);
    k_scan2<<<1, 256, 0, stream>>>(bsums, nb);
    k_scan3<<<nb, 256, 0, stream>>>(offs, bsums, N);
    k_fill <<<eb, 256, 0, stream>>>(src, dst, gid, dinv, cval, offs, cursor, csr, E);
    k_agg  <<<4096, 512, 0, stream>>>(gene, gid, deg, csr, offs, indeg, aggU, N);
    k_gemm <<<512, 512, 0, stream>>>(aggU, W1, b1, cval, s_acc, N);
    k_final<<<1, 128, 0, stream>>>(s_acc, W2, b2, out, 1.0f / (float)N);
}

// Round 2
// 528.443 us; speedup vs baseline: 1.6835x; 1.6835x over previous
//
#include <hip/hip_runtime.h>

#define NG 20000   // NUM_GENES
#define BB 8       // batch
#define FD 128     // feature dim

typedef unsigned int uint;
typedef unsigned short ushort;

// ---------------- small setup kernels ----------------

__global__ void k_init(float* deg, int* cursor, float* s_acc, int N) {
    int i = blockIdx.x * blockDim.x + threadIdx.x;
    if (i < N) { deg[i] = 1.0f; cursor[i] = 0; }
    if (i < BB * FD) s_acc[i] = 0.0f;
}

__global__ void k_count(const int* __restrict__ dst, float* deg, int E) {
    int e = blockIdx.x * blockDim.x + threadIdx.x;
    if (e < E) atomicAdd(&deg[dst[e]], 1.0f);
}

__global__ void k_node(const float* __restrict__ deg, float* dinv, float* cval,
                       int* indeg, int N) {
    int i = blockIdx.x * blockDim.x + threadIdx.x;
    if (i < N) {
        float d = deg[i];
        dinv[i]  = rsqrtf(d);
        cval[i]  = 1.0f / d;          // self-loop contribution to c[i]
        indeg[i] = (int)d - 1;        // in-degree excluding self loop
    }
}

// exclusive scan of indeg -> offs (2-level, blockDim must be 256)
__global__ void k_scan1(const int* __restrict__ indeg, int* offs, int* bsums, int N) {
    __shared__ int sd[256];
    int t = threadIdx.x, idx = blockIdx.x * 256 + t;
    int v = (idx < N) ? indeg[idx] : 0;
    sd[t] = v; __syncthreads();
    for (int o = 1; o < 256; o <<= 1) {
        int x = (t >= o) ? sd[t - o] : 0;
        __syncthreads();
        sd[t] += x;
        __syncthreads();
    }
    if (idx < N) offs[idx] = sd[t] - v;
    if (t == 255) bsums[blockIdx.x] = sd[255];
}

__global__ void k_scan2(int* bsums, int nb) {
    __shared__ int sd[256];
    int t = threadIdx.x;
    int v = (t < nb) ? bsums[t] : 0;
    sd[t] = v; __syncthreads();
    for (int o = 1; o < 256; o <<= 1) {
        int x = (t >= o) ? sd[t - o] : 0;
        __syncthreads();
        sd[t] += x;
        __syncthreads();
    }
    if (t < nb) bsums[t] = sd[t] - v;   // exclusive
}

__global__ void k_scan3(int* offs, const int* __restrict__ bsums, int N) {
    int i = blockIdx.x * blockDim.x + threadIdx.x;
    if (i < N) offs[i] += bsums[blockIdx.x];  // blockDim==256 so i>>8==blockIdx
}

// build CSR by dst; also accumulate c[src] += norm. csr entry: {gene_row(src), norm bits}
__global__ void k_fill(const int* __restrict__ src, const int* __restrict__ dst,
                       const int* __restrict__ gid, const float* __restrict__ dinv,
                       float* cval, const int* __restrict__ offs, int* cursor,
                       int2* csr, int E) {
    int e = blockIdx.x * blockDim.x + threadIdx.x;
    if (e >= E) return;
    int s = src[e], d = dst[e];
    float nrm = dinv[s] * dinv[d];
    atomicAdd(&cval[s], nrm);
    int pos = atomicAdd(&cursor[d], 1);
    csr[offs[d] + pos] = make_int2(gid[s], __float_as_int(nrm));
}

// ---------------- h = gene @ W1, stored bf16 transposed to [g][b][j] ----------------
// block 512 = 8 waves; 8 genes (64 rows) per block; W1 (64KB) + xs (32KB) in LDS.
__device__ __forceinline__ ushort f2bf(float x) {
    uint u = __float_as_uint(x);
    u += 0x7FFFu + ((u >> 16) & 1u);   // round to nearest even
    return (ushort)(u >> 16);
}

__global__ __launch_bounds__(512, 1)
void k_h(const float* __restrict__ gene, const float* __restrict__ W1,
         ushort* __restrict__ h2) {
    __shared__ float W1s[128 * 128];   // 64 KB
    __shared__ float xs[64 * 128];     // 32 KB  [row = gi*8+b][k]
    int t = threadIdx.x;
    for (int i = t; i < 16384; i += 512) W1s[i] = W1[i];

    int g0 = blockIdx.x * 8;
#pragma unroll
    for (int s = 0; s < 4; s++) {
        int f4  = t + s * 512;        // float4 index, 0..2047
        int row = f4 >> 5;            // gi*8 + b
        int k4  = f4 & 31;
        int gi = row >> 3, b = row & 7;
        float4 v = *(const float4*)(gene + ((size_t)b * NG + g0 + gi) * 128 + k4 * 4);
        *(float4*)&xs[f4 * 4] = v;
    }
    __syncthreads();

    int j0 = (t & 31) * 4;
    int r  = t >> 5;                   // row group: rows r*4 .. r*4+3
    const float* x0 = &xs[(r * 4 + 0) * 128];
    const float* x1 = &xs[(r * 4 + 1) * 128];
    const float* x2 = &xs[(r * 4 + 2) * 128];
    const float* x3 = &xs[(r * 4 + 3) * 128];
    float4 a0 = make_float4(0.f,0.f,0.f,0.f), a1 = a0, a2 = a0, a3 = a0;
#pragma unroll 4
    for (int k = 0; k < 128; k++) {
        float4 w = *(const float4*)&W1s[k * 128 + j0];
        float v0 = x0[k], v1 = x1[k], v2 = x2[k], v3 = x3[k];
        a0.x += v0 * w.x; a0.y += v0 * w.y; a0.z += v0 * w.z; a0.w += v0 * w.w;
        a1.x += v1 * w.x; a1.y += v1 * w.y; a1.z += v1 * w.z; a1.w += v1 * w.w;
        a2.x += v2 * w.x; a2.y += v2 * w.y; a2.z += v2 * w.z; a2.w += v2 * w.w;
        a3.x += v3 * w.x; a3.y += v3 * w.y; a3.z += v3 * w.z; a3.w += v3 * w.w;
    }
    float4 accs[4] = { a0, a1, a2, a3 };
#pragma unroll
    for (int q = 0; q < 4; q++) {
        int row = r * 4 + q;
        int gi = row >> 3, b = row & 7;
        ushort4 o;
        o.x = f2bf(accs[q].x); o.y = f2bf(accs[q].y);
        o.z = f2bf(accs[q].z); o.w = f2bf(accs[q].w);
        *(ushort4*)&h2[((size_t)(g0 + gi) * 8 + b) * 128 + j0] = o;
    }
}

// ---------------- fused gather + relu + weighted reduce ----------------
// block 512; per node: block reads one contiguous 2KB bf16 row per edge.
// thread t owns (b = t>>6, features j=(t&63)*2, +1); s_acc flat index = 2t.
__device__ __forceinline__ float bf_lo(uint u) { return __uint_as_float(u << 16); }
__device__ __forceinline__ float bf_hi(uint u) { return __uint_as_float(u & 0xFFFF0000u); }

__global__ __launch_bounds__(512)
void k_aggf(const uint* __restrict__ h2u, const int* __restrict__ gid,
            const float* __restrict__ deg, const int2* __restrict__ csr,
            const int* __restrict__ offs, const int* __restrict__ indeg,
            const float* __restrict__ cval, const float* __restrict__ b1,
            float* __restrict__ s_acc, int N) {
    int t = threadIdx.x;
    int j = (t & 63) * 2;
    float bx = b1[j], by = b1[j + 1];
    float sx = 0.f, sy = 0.f;
    for (int i = blockIdx.x; i < N; i += gridDim.x) {
        int start = offs[i], cnt = indeg[i];
        float w = 1.0f / deg[i];                       // self-loop dinv^2
        uint us = h2u[(size_t)gid[i] * 512 + t];
        float ax = w * bf_lo(us), ay = w * bf_hi(us);
        int e = start, end = start + cnt;
        for (; e + 1 < end; e += 2) {
            int2 c0 = csr[e], c1 = csr[e + 1];
            uint u0 = h2u[(size_t)c0.x * 512 + t];
            uint u1 = h2u[(size_t)c1.x * 512 + t];
            float n0 = __int_as_float(c0.y), n1 = __int_as_float(c1.y);
            ax += n0 * bf_lo(u0); ay += n0 * bf_hi(u0);
            ax += n1 * bf_lo(u1); ay += n1 * bf_hi(u1);
        }
        if (e < end) {
            int2 c0 = csr[e];
            uint u0 = h2u[(size_t)c0.x * 512 + t];
            float n0 = __int_as_float(c0.y);
            ax += n0 * bf_lo(u0); ay += n0 * bf_hi(u0);
        }
        float cv = cval[i];
        sx += cv * fmaxf(ax + bx, 0.f);
        sy += cv * fmaxf(ay + by, 0.f);
    }
    atomicAdd(&s_acc[2 * t],     sx);
    atomicAdd(&s_acc[2 * t + 1], sy);
}

// out[b][j] = (s[b] @ W2)[j] / N + b2[j]   (tiny: 8x128x128)
__global__ void k_final(const float* __restrict__ s_acc, const float* __restrict__ W2,
                        const float* __restrict__ b2, float* __restrict__ out, float invN) {
    __shared__ float ss[1024];
    int t = threadIdx.x;  // 128 threads
    for (int idx = t; idx < 1024; idx += 128) ss[idx] = s_acc[idx];
    __syncthreads();
    float acc[8];
#pragma unroll
    for (int b = 0; b < 8; b++) acc[b] = 0.f;
    for (int k = 0; k < 128; k++) {
        float w = W2[k * 128 + t];
#pragma unroll
        for (int b = 0; b < 8; b++) acc[b] += ss[b * 128 + k] * w;
    }
    float bb = b2[t];
#pragma unroll
    for (int b = 0; b < 8; b++) out[b * 128 + t] = acc[b] * invN + bb;
}

// ---------------- launcher ----------------

extern "C" void kernel_launch(void* const* d_in, const int* in_sizes, int n_in,
                              void* d_out, int out_size, void* d_ws, size_t ws_size,
                              hipStream_t stream) {
    const float* gene = (const float*)d_in[0];
    const float* W1   = (const float*)d_in[1];
    const float* b1   = (const float*)d_in[2];
    const float* W2   = (const float*)d_in[3];
    const float* b2   = (const float*)d_in[4];
    const int*   gid  = (const int*)d_in[5];
    const int*   eidx = (const int*)d_in[6];
    int N = in_sizes[5];
    int E = in_sizes[6] / 2;
    const int* src = eidx;
    const int* dst = eidx + E;
    float* out = (float*)d_out;

    char* p = (char*)d_ws;
    auto alloc = [&](size_t bytes) -> char* {
        char* r = p; p += (bytes + 255) & ~(size_t)255; return r;
    };
    float* deg    = (float*)alloc((size_t)N * 4);
    float* dinv   = (float*)alloc((size_t)N * 4);
    float* cval   = (float*)alloc((size_t)N * 4);
    int*   indeg  = (int*)  alloc((size_t)N * 4);
    int*   offs   = (int*)  alloc((size_t)N * 4);
    int*   cursor = (int*)  alloc((size_t)N * 4);
    int*   bsums  = (int*)  alloc(256 * 4);
    int2*  csr    = (int2*) alloc((size_t)E * 8);
    float* s_acc  = (float*)alloc(1024 * 4);
    ushort* h2    = (ushort*)alloc((size_t)NG * BB * FD * 2);   // 41 MB, bf16 [g][b][j]

    int nb = (N + 255) / 256;   // 196 (must be <= 256 for scan2)
    int eb = (E + 255) / 256;

    k_init <<<nb, 256, 0, stream>>>(deg, cursor, s_acc, N);
    k_count<<<eb, 256, 0, stream>>>(dst, deg, E);
    k_node <<<nb, 256, 0, stream>>>(deg, dinv, cval, indeg, N);
    k_scan1<<<nb, 256, 0, stream>>>(indeg, offs, bsums, N);
    k_scan2<<<1, 256, 0, stream>>>(bsums, nb);
    k_scan3<<<nb, 256, 0, stream>>>(offs, bsums, N);
    k_fill <<<eb, 256, 0, stream>>>(src, dst, gid, dinv, cval, offs, cursor, csr, E);
    k_h    <<<NG / 8, 512, 0, stream>>>(gene, W1, h2);
    k_aggf <<<2048, 512, 0, stream>>>((const uint*)h2, gid, deg, csr, offs, indeg,
                                      cval, b1, s_acc, N);
    k_final<<<1, 128, 0, stream>>>(s_acc, W2, b2, out, 1.0f / (float)N);
}

// Round 3
// 485.676 us; speedup vs baseline: 1.8318x; 1.0881x over previous
//
#include <hip/hip_runtime.h>

#define NG 20000   // NUM_GENES
#define BB 8       // batch
#define FD 128     // feature dim

typedef unsigned int uint;
typedef unsigned short ushort;

// ---------------- small setup kernels ----------------

__global__ void k_init(float* deg, int* cursor, float* s_acc, int N) {
    int i = blockIdx.x * blockDim.x + threadIdx.x;
    if (i < N) { deg[i] = 1.0f; cursor[i] = 0; }
    if (i < BB * FD) s_acc[i] = 0.0f;
}

__global__ void k_count(const int* __restrict__ dst, float* deg, int E) {
    int e = blockIdx.x * blockDim.x + threadIdx.x;
    if (e < E) atomicAdd(&deg[dst[e]], 1.0f);
}

__global__ void k_node(const float* __restrict__ deg, float* dinv, float* cval,
                       int* indeg, int N) {
    int i = blockIdx.x * blockDim.x + threadIdx.x;
    if (i < N) {
        float d = deg[i];
        dinv[i]  = rsqrtf(d);
        cval[i]  = 1.0f / d;          // self-loop contribution to c[i]
        indeg[i] = (int)d - 1;        // in-degree excluding self loop
    }
}

// exclusive scan of indeg -> offs (2-level, blockDim must be 256)
__global__ void k_scan1(const int* __restrict__ indeg, int* offs, int* bsums, int N) {
    __shared__ int sd[256];
    int t = threadIdx.x, idx = blockIdx.x * 256 + t;
    int v = (idx < N) ? indeg[idx] : 0;
    sd[t] = v; __syncthreads();
    for (int o = 1; o < 256; o <<= 1) {
        int x = (t >= o) ? sd[t - o] : 0;
        __syncthreads();
        sd[t] += x;
        __syncthreads();
    }
    if (idx < N) offs[idx] = sd[t] - v;
    if (t == 255) bsums[blockIdx.x] = sd[255];
}

__global__ void k_scan2(int* bsums, int nb) {
    __shared__ int sd[256];
    int t = threadIdx.x;
    int v = (t < nb) ? bsums[t] : 0;
    sd[t] = v; __syncthreads();
    for (int o = 1; o < 256; o <<= 1) {
        int x = (t >= o) ? sd[t - o] : 0;
        __syncthreads();
        sd[t] += x;
        __syncthreads();
    }
    if (t < nb) bsums[t] = sd[t] - v;   // exclusive
}

__global__ void k_scan3(int* offs, const int* __restrict__ bsums, int N) {
    int i = blockIdx.x * blockDim.x + threadIdx.x;
    if (i < N) offs[i] += bsums[blockIdx.x];  // blockDim==256 so i>>8==blockIdx
}

// build CSR by dst; also accumulate c[src] += norm. csr entry: {gene_row(src), norm bits}
__global__ void k_fill(const int* __restrict__ src, const int* __restrict__ dst,
                       const int* __restrict__ gid, const float* __restrict__ dinv,
                       float* cval, const int* __restrict__ offs, int* cursor,
                       int2* csr, int E) {
    int e = blockIdx.x * blockDim.x + threadIdx.x;
    if (e >= E) return;
    int s = src[e], d = dst[e];
    float nrm = dinv[s] * dinv[d];
    atomicAdd(&cval[s], nrm);
    int pos = atomicAdd(&cursor[d], 1);
    csr[offs[d] + pos] = make_int2(gid[s], __float_as_int(nrm));
}

// ---------------- h = gene @ W1, stored bf16 BATCH-MAJOR: h[b][g][j] ----------------
// block 512 = 8 waves; 8 genes (64 rows) per block; W1 (64KB) + xs (32KB) in LDS.
__device__ __forceinline__ ushort f2bf(float x) {
    uint u = __float_as_uint(x);
    u += 0x7FFFu + ((u >> 16) & 1u);   // round to nearest even
    return (ushort)(u >> 16);
}

__global__ __launch_bounds__(512, 1)
void k_h(const float* __restrict__ gene, const float* __restrict__ W1,
         ushort* __restrict__ h2) {
    __shared__ float W1s[128 * 128];   // 64 KB
    __shared__ float xs[64 * 128];     // 32 KB  [row = gi*8+b][k]
    int t = threadIdx.x;
    for (int i = t; i < 16384; i += 512) W1s[i] = W1[i];

    int g0 = blockIdx.x * 8;
#pragma unroll
    for (int s = 0; s < 4; s++) {
        int f4  = t + s * 512;        // float4 index, 0..2047
        int row = f4 >> 5;            // gi*8 + b
        int k4  = f4 & 31;
        int gi = row >> 3, b = row & 7;
        float4 v = *(const float4*)(gene + ((size_t)b * NG + g0 + gi) * 128 + k4 * 4);
        *(float4*)&xs[f4 * 4] = v;
    }
    __syncthreads();

    int j0 = (t & 31) * 4;
    int r  = t >> 5;                   // row group: rows r*4 .. r*4+3
    const float* x0 = &xs[(r * 4 + 0) * 128];
    const float* x1 = &xs[(r * 4 + 1) * 128];
    const float* x2 = &xs[(r * 4 + 2) * 128];
    const float* x3 = &xs[(r * 4 + 3) * 128];
    float4 a0 = make_float4(0.f,0.f,0.f,0.f), a1 = a0, a2 = a0, a3 = a0;
#pragma unroll 4
    for (int k = 0; k < 128; k++) {
        float4 w = *(const float4*)&W1s[k * 128 + j0];
        float v0 = x0[k], v1 = x1[k], v2 = x2[k], v3 = x3[k];
        a0.x += v0 * w.x; a0.y += v0 * w.y; a0.z += v0 * w.z; a0.w += v0 * w.w;
        a1.x += v1 * w.x; a1.y += v1 * w.y; a1.z += v1 * w.z; a1.w += v1 * w.w;
        a2.x += v2 * w.x; a2.y += v2 * w.y; a2.z += v2 * w.z; a2.w += v2 * w.w;
        a3.x += v3 * w.x; a3.y += v3 * w.y; a3.z += v3 * w.z; a3.w += v3 * w.w;
    }
    float4 accs[4] = { a0, a1, a2, a3 };
#pragma unroll
    for (int q = 0; q < 4; q++) {
        int row = r * 4 + q;
        int gi = row >> 3, b = row & 7;
        ushort4 o;
        o.x = f2bf(accs[q].x); o.y = f2bf(accs[q].y);
        o.z = f2bf(accs[q].z); o.w = f2bf(accs[q].w);
        // batch-major: h2[b][g][j]
        *(ushort4*)&h2[((size_t)b * NG + g0 + gi) * 128 + j0] = o;
    }
}

// ---------------- fused gather + relu + weighted reduce, XCD-sharded by batch ----------------
// blockIdx % 8 = batch (round-robin blockIdx->XCD keeps each XCD on one 10.25MB table).
// Each 64-lane wave owns one node; lane holds 1 dword (2 bf16 feats); edge loop unrolled x4.
__device__ __forceinline__ float bf_lo(uint u) { return __uint_as_float(u << 16); }
__device__ __forceinline__ float bf_hi(uint u) { return __uint_as_float(u & 0xFFFF0000u); }

__global__ __launch_bounds__(512)
void k_aggf(const uint* __restrict__ hb, const int* __restrict__ gid,
            const float* __restrict__ deg, const int2* __restrict__ csr,
            const int* __restrict__ offs, const int* __restrict__ indeg,
            const float* __restrict__ cval, const float* __restrict__ b1,
            float* __restrict__ s_acc, int N, int nwaves) {
    int b   = blockIdx.x & 7;
    int lb  = blockIdx.x >> 3;
    int wid = threadIdx.x >> 6, lane = threadIdx.x & 63;
    int w   = lb * 8 + wid;                      // wave slot within this batch
    const uint* base = hb + (size_t)b * NG * 64 + lane;
    int j = lane * 2;
    float bx = b1[j], by = b1[j + 1];
    float sx = 0.f, sy = 0.f;

    for (int i = w; i < N; i += nwaves) {
        float winv = 1.0f / deg[i];
        uint us = base[(size_t)gid[i] * 64];
        float ax = winv * bf_lo(us), ay = winv * bf_hi(us);
        int e = offs[i], end = e + indeg[i];
        for (; e + 3 < end; e += 4) {
            int2 c0 = csr[e], c1 = csr[e + 1], c2 = csr[e + 2], c3 = csr[e + 3];
            uint u0 = base[(size_t)c0.x * 64];
            uint u1 = base[(size_t)c1.x * 64];
            uint u2 = base[(size_t)c2.x * 64];
            uint u3 = base[(size_t)c3.x * 64];
            float n0 = __int_as_float(c0.y), n1 = __int_as_float(c1.y);
            float n2 = __int_as_float(c2.y), n3 = __int_as_float(c3.y);
            ax += n0 * bf_lo(u0); ay += n0 * bf_hi(u0);
            ax += n1 * bf_lo(u1); ay += n1 * bf_hi(u1);
            ax += n2 * bf_lo(u2); ay += n2 * bf_hi(u2);
            ax += n3 * bf_lo(u3); ay += n3 * bf_hi(u3);
        }
        for (; e < end; e++) {
            int2 c0 = csr[e];
            uint u0 = base[(size_t)c0.x * 64];
            float n0 = __int_as_float(c0.y);
            ax += n0 * bf_lo(u0); ay += n0 * bf_hi(u0);
        }
        float cv = cval[i];
        sx += cv * fmaxf(ax + bx, 0.f);
        sy += cv * fmaxf(ay + by, 0.f);
    }

    // block-level reduction: 8 waves (same batch) -> 128 floats -> 1 atomic each
    __shared__ float red[8][128];
    red[wid][j]     = sx;
    red[wid][j + 1] = sy;
    __syncthreads();
    int t = threadIdx.x;
    if (t < 128) {
        float s = 0.f;
#pragma unroll
        for (int wv = 0; wv < 8; wv++) s += red[wv][t];
        atomicAdd(&s_acc[b * 128 + t], s);
    }
}

// out[b][j] = (s[b] @ W2)[j] / N + b2[j]   (tiny: 8x128x128)
__global__ void k_final(const float* __restrict__ s_acc, const float* __restrict__ W2,
                        const float* __restrict__ b2, float* __restrict__ out, float invN) {
    __shared__ float ss[1024];
    int t = threadIdx.x;  // 128 threads
    for (int idx = t; idx < 1024; idx += 128) ss[idx] = s_acc[idx];
    __syncthreads();
    float acc[8];
#pragma unroll
    for (int b = 0; b < 8; b++) acc[b] = 0.f;
    for (int k = 0; k < 128; k++) {
        float w = W2[k * 128 + t];
#pragma unroll
        for (int b = 0; b < 8; b++) acc[b] += ss[b * 128 + k] * w;
    }
    float bb = b2[t];
#pragma unroll
    for (int b = 0; b < 8; b++) out[b * 128 + t] = acc[b] * invN + bb;
}

// ---------------- launcher ----------------

extern "C" void kernel_launch(void* const* d_in, const int* in_sizes, int n_in,
                              void* d_out, int out_size, void* d_ws, size_t ws_size,
                              hipStream_t stream) {
    const float* gene = (const float*)d_in[0];
    const float* W1   = (const float*)d_in[1];
    const float* b1   = (const float*)d_in[2];
    const float* W2   = (const float*)d_in[3];
    const float* b2   = (const float*)d_in[4];
    const int*   gid  = (const int*)d_in[5];
    const int*   eidx = (const int*)d_in[6];
    int N = in_sizes[5];
    int E = in_sizes[6] / 2;
    const int* src = eidx;
    const int* dst = eidx + E;
    float* out = (float*)d_out;

    char* p = (char*)d_ws;
    auto alloc = [&](size_t bytes) -> char* {
        char* r = p; p += (bytes + 255) & ~(size_t)255; return r;
    };
    float* deg    = (float*)alloc((size_t)N * 4);
    float* dinv   = (float*)alloc((size_t)N * 4);
    float* cval   = (float*)alloc((size_t)N * 4);
    int*   indeg  = (int*)  alloc((size_t)N * 4);
    int*   offs   = (int*)  alloc((size_t)N * 4);
    int*   cursor = (int*)  alloc((size_t)N * 4);
    int*   bsums  = (int*)  alloc(256 * 4);
    int2*  csr    = (int2*) alloc((size_t)E * 8);
    float* s_acc  = (float*)alloc(1024 * 4);
    ushort* h2    = (ushort*)alloc((size_t)NG * BB * FD * 2);   // 41 MB, bf16 [b][g][j]

    int nb = (N + 255) / 256;   // 196 (must be <= 256 for scan2)
    int eb = (E + 255) / 256;

    const int NBLK = 2048;            // per batch: 256 blocks * 8 waves = 2048 wave slots
    const int NWAVES = (NBLK / 8) * 8;

    k_init <<<nb, 256, 0, stream>>>(deg, cursor, s_acc, N);
    k_count<<<eb, 256, 0, stream>>>(dst, deg, E);
    k_node <<<nb, 256, 0, stream>>>(deg, dinv, cval, indeg, N);
    k_scan1<<<nb, 256, 0, stream>>>(indeg, offs, bsums, N);
    k_scan2<<<1, 256, 0, stream>>>(bsums, nb);
    k_scan3<<<nb, 256, 0, stream>>>(offs, bsums, N);
    k_fill <<<eb, 256, 0, stream>>>(src, dst, gid, dinv, cval, offs, cursor, csr, E);
    k_h    <<<NG / 8, 512, 0, stream>>>(gene, W1, h2);
    k_aggf <<<NBLK, 512, 0, stream>>>((const uint*)h2, gid, deg, csr, offs, indeg,
                                      cval, b1, s_acc, N, NWAVES);
    k_final<<<1, 128, 0, stream>>>(s_acc, W2, b2, out, 1.0f / (float)N);
}

// Round 4
// 432.200 us; speedup vs baseline: 2.0584x; 1.1237x over previous
//
#include <hip/hip_runtime.h>

#define NG 20000   // NUM_GENES
#define BB 8       // batch
#define FD 128     // feature dim

typedef unsigned int uint;
typedef unsigned short ushort;

// ---------------- small setup kernels ----------------

__global__ void k_init(float* deg, int* cursor, float* s_acc, int N) {
    int i = blockIdx.x * blockDim.x + threadIdx.x;
    if (i < N) { deg[i] = 1.0f; cursor[i] = 0; }
    if (i < BB * FD) s_acc[i] = 0.0f;
}

__global__ void k_count(const int* __restrict__ dst, float* deg, int E) {
    int e = blockIdx.x * blockDim.x + threadIdx.x;
    if (e < E) atomicAdd(&deg[dst[e]], 1.0f);
}

__global__ void k_node(const float* __restrict__ deg, float* dinv, float* cval,
                       float* wself, int* indeg, int N) {
    int i = blockIdx.x * blockDim.x + threadIdx.x;
    if (i < N) {
        float d = deg[i];
        dinv[i]  = rsqrtf(d);
        float iv = 1.0f / d;
        cval[i]  = iv;                // self-loop contribution to c[i]
        wself[i] = iv;                // dinv^2 for the self term
        indeg[i] = (int)d - 1;        // in-degree excluding self loop
    }
}

// exclusive scan of indeg -> offs (2-level, blockDim must be 256)
__global__ void k_scan1(const int* __restrict__ indeg, int* offs, int* bsums, int N) {
    __shared__ int sd[256];
    int t = threadIdx.x, idx = blockIdx.x * 256 + t;
    int v = (idx < N) ? indeg[idx] : 0;
    sd[t] = v; __syncthreads();
    for (int o = 1; o < 256; o <<= 1) {
        int x = (t >= o) ? sd[t - o] : 0;
        __syncthreads();
        sd[t] += x;
        __syncthreads();
    }
    if (idx < N) offs[idx] = sd[t] - v;
    if (t == 255) bsums[blockIdx.x] = sd[255];
}

__global__ void k_scan2(int* bsums, int nb) {
    __shared__ int sd[256];
    int t = threadIdx.x;
    int v = (t < nb) ? bsums[t] : 0;
    sd[t] = v; __syncthreads();
    for (int o = 1; o < 256; o <<= 1) {
        int x = (t >= o) ? sd[t - o] : 0;
        __syncthreads();
        sd[t] += x;
        __syncthreads();
    }
    if (t < nb) bsums[t] = sd[t] - v;   // exclusive
}

__global__ void k_scan3(int* offs, const int* __restrict__ bsums, int N) {
    int i = blockIdx.x * blockDim.x + threadIdx.x;
    if (i < N) offs[i] += bsums[blockIdx.x];  // blockDim==256 so i>>8==blockIdx
}

// build CSR by dst; also accumulate c[src] += norm. csr entry: {gene_row(src), norm bits}
__global__ void k_fill(const int* __restrict__ src, const int* __restrict__ dst,
                       const int* __restrict__ gid, const float* __restrict__ dinv,
                       float* cval, const int* __restrict__ offs, int* cursor,
                       int2* csr, int E) {
    int e = blockIdx.x * blockDim.x + threadIdx.x;
    if (e >= E) return;
    int s = src[e], d = dst[e];
    float nrm = dinv[s] * dinv[d];
    atomicAdd(&cval[s], nrm);
    int pos = atomicAdd(&cursor[d], 1);
    csr[offs[d] + pos] = make_int2(gid[s], __float_as_int(nrm));
}

// ---------------- h = gene @ W1, stored bf16 BATCH-MAJOR: h[b][g][j] ----------------
__device__ __forceinline__ ushort f2bf(float x) {
    uint u = __float_as_uint(x);
    u += 0x7FFFu + ((u >> 16) & 1u);   // round to nearest even
    return (ushort)(u >> 16);
}

__global__ __launch_bounds__(512, 1)
void k_h(const float* __restrict__ gene, const float* __restrict__ W1,
         ushort* __restrict__ h2) {
    __shared__ float W1s[128 * 128];   // 64 KB
    __shared__ float xs[64 * 128];     // 32 KB  [row = gi*8+b][k]
    int t = threadIdx.x;
    for (int i = t; i < 16384; i += 512) W1s[i] = W1[i];

    int g0 = blockIdx.x * 8;
#pragma unroll
    for (int s = 0; s < 4; s++) {
        int f4  = t + s * 512;        // float4 index, 0..2047
        int row = f4 >> 5;            // gi*8 + b
        int k4  = f4 & 31;
        int gi = row >> 3, b = row & 7;
        float4 v = *(const float4*)(gene + ((size_t)b * NG + g0 + gi) * 128 + k4 * 4);
        *(float4*)&xs[f4 * 4] = v;
    }
    __syncthreads();

    int j0 = (t & 31) * 4;
    int r  = t >> 5;                   // row group: rows r*4 .. r*4+3
    const float* x0 = &xs[(r * 4 + 0) * 128];
    const float* x1 = &xs[(r * 4 + 1) * 128];
    const float* x2 = &xs[(r * 4 + 2) * 128];
    const float* x3 = &xs[(r * 4 + 3) * 128];
    float4 a0 = make_float4(0.f,0.f,0.f,0.f), a1 = a0, a2 = a0, a3 = a0;
#pragma unroll 4
    for (int k = 0; k < 128; k++) {
        float4 w = *(const float4*)&W1s[k * 128 + j0];
        float v0 = x0[k], v1 = x1[k], v2 = x2[k], v3 = x3[k];
        a0.x += v0 * w.x; a0.y += v0 * w.y; a0.z += v0 * w.z; a0.w += v0 * w.w;
        a1.x += v1 * w.x; a1.y += v1 * w.y; a1.z += v1 * w.z; a1.w += v1 * w.w;
        a2.x += v2 * w.x; a2.y += v2 * w.y; a2.z += v2 * w.z; a2.w += v2 * w.w;
        a3.x += v3 * w.x; a3.y += v3 * w.y; a3.z += v3 * w.z; a3.w += v3 * w.w;
    }
    float4 accs[4] = { a0, a1, a2, a3 };
#pragma unroll
    for (int q = 0; q < 4; q++) {
        int row = r * 4 + q;
        int gi = row >> 3, b = row & 7;
        ushort4 o;
        o.x = f2bf(accs[q].x); o.y = f2bf(accs[q].y);
        o.z = f2bf(accs[q].z); o.w = f2bf(accs[q].w);
        // batch-major: h2[b][g][j]
        *(ushort4*)&h2[((size_t)b * NG + g0 + gi) * 128 + j0] = o;
    }
}

// ---------------- fused gather + relu + weighted reduce (scalarized streaming CSR) ----------------
// blockIdx % 8 = batch (round-robin blockIdx->XCD keeps each XCD on one 10.25MB table).
// Each wave owns a CONTIGUOUS chunk of nodes; all bookkeeping (offs/indeg/csr/norm/addresses)
// is wave-uniform -> forced into SGPRs via readfirstlane: csr entries come via s_load,
// row gathers are saddr-form global_load_dword (scalar base + lane*4), norm is an SGPR
// fmac operand. 8 row-loads in flight per wave.
__device__ __forceinline__ float bf_lo(uint u) { return __uint_as_float(u << 16); }
__device__ __forceinline__ float bf_hi(uint u) { return __uint_as_float(u & 0xFFFF0000u); }

__global__ __launch_bounds__(512)
void k_aggs(const uint* __restrict__ hb, const int* __restrict__ gid,
            const float* __restrict__ wself, const int2* __restrict__ csr,
            const int* __restrict__ offs, const int* __restrict__ indeg,
            const float* __restrict__ cval, const float* __restrict__ b1,
            float* __restrict__ s_acc, int N, int npw) {
    int b    = blockIdx.x & 7;
    int wid  = threadIdx.x >> 6, lane = threadIdx.x & 63;
    int w    = __builtin_amdgcn_readfirstlane((blockIdx.x >> 3) * 8 + wid);
    const uint* base = hb + (size_t)b * NG * 64;   // scalar base of this batch's table
    int j = lane * 2;
    float bx = b1[j], by = b1[j + 1];
    float sx = 0.f, sy = 0.f;

    int i0 = w * npw;
    int i1 = min(N, i0 + npw);
    for (int i = i0; i < i1; ++i) {
        float wv  = wself[i];          // scalar loads (i is SGPR)
        int   gs  = gid[i];
        int   e   = offs[i];
        int   cnt = indeg[i];
        float cv  = cval[i];
        const uint* rp = base + (size_t)gs * 64;
        uint us = rp[lane];
        float ax = wv * bf_lo(us), ay = wv * bf_hi(us);
        int end = e + cnt;
        for (; e + 7 < end; e += 8) {
            int2 c0 = csr[e],     c1 = csr[e + 1], c2 = csr[e + 2], c3 = csr[e + 3];
            int2 c4 = csr[e + 4], c5 = csr[e + 5], c6 = csr[e + 6], c7 = csr[e + 7];
            const uint* r0 = base + (size_t)c0.x * 64;
            const uint* r1 = base + (size_t)c1.x * 64;
            const uint* r2 = base + (size_t)c2.x * 64;
            const uint* r3 = base + (size_t)c3.x * 64;
            const uint* r4 = base + (size_t)c4.x * 64;
            const uint* r5 = base + (size_t)c5.x * 64;
            const uint* r6 = base + (size_t)c6.x * 64;
            const uint* r7 = base + (size_t)c7.x * 64;
            uint u0 = r0[lane], u1 = r1[lane], u2 = r2[lane], u3 = r3[lane];
            uint u4 = r4[lane], u5 = r5[lane], u6 = r6[lane], u7 = r7[lane];
            float n0 = __int_as_float(c0.y), n1 = __int_as_float(c1.y);
            float n2 = __int_as_float(c2.y), n3 = __int_as_float(c3.y);
            float n4 = __int_as_float(c4.y), n5 = __int_as_float(c5.y);
            float n6 = __int_as_float(c6.y), n7 = __int_as_float(c7.y);
            ax = fmaf(n0, bf_lo(u0), ax); ay = fmaf(n0, bf_hi(u0), ay);
            ax = fmaf(n1, bf_lo(u1), ax); ay = fmaf(n1, bf_hi(u1), ay);
            ax = fmaf(n2, bf_lo(u2), ax); ay = fmaf(n2, bf_hi(u2), ay);
            ax = fmaf(n3, bf_lo(u3), ax); ay = fmaf(n3, bf_hi(u3), ay);
            ax = fmaf(n4, bf_lo(u4), ax); ay = fmaf(n4, bf_hi(u4), ay);
            ax = fmaf(n5, bf_lo(u5), ax); ay = fmaf(n5, bf_hi(u5), ay);
            ax = fmaf(n6, bf_lo(u6), ax); ay = fmaf(n6, bf_hi(u6), ay);
            ax = fmaf(n7, bf_lo(u7), ax); ay = fmaf(n7, bf_hi(u7), ay);
        }
        for (; e < end; ++e) {
            int2 c0 = csr[e];
            const uint* r0 = base + (size_t)c0.x * 64;
            uint u0 = r0[lane];
            float n0 = __int_as_float(c0.y);
            ax = fmaf(n0, bf_lo(u0), ax); ay = fmaf(n0, bf_hi(u0), ay);
        }
        sx += cv * fmaxf(ax + bx, 0.f);
        sy += cv * fmaxf(ay + by, 0.f);
    }

    // block-level reduction: 8 waves (same batch) -> 128 floats -> 1 atomic each
    __shared__ float red[8][128];
    red[wid][j]     = sx;
    red[wid][j + 1] = sy;
    __syncthreads();
    int t = threadIdx.x;
    if (t < 128) {
        float s = 0.f;
#pragma unroll
        for (int wv = 0; wv < 8; wv++) s += red[wv][t];
        atomicAdd(&s_acc[b * 128 + t], s);
    }
}

// out[b][j] = (s[b] @ W2)[j] / N + b2[j]   (tiny: 8x128x128)
__global__ void k_final(const float* __restrict__ s_acc, const float* __restrict__ W2,
                        const float* __restrict__ b2, float* __restrict__ out, float invN) {
    __shared__ float ss[1024];
    int t = threadIdx.x;  // 128 threads
    for (int idx = t; idx < 1024; idx += 128) ss[idx] = s_acc[idx];
    __syncthreads();
    float acc[8];
#pragma unroll
    for (int b = 0; b < 8; b++) acc[b] = 0.f;
    for (int k = 0; k < 128; k++) {
        float w = W2[k * 128 + t];
#pragma unroll
        for (int b = 0; b < 8; b++) acc[b] += ss[b * 128 + k] * w;
    }
    float bb = b2[t];
#pragma unroll
    for (int b = 0; b < 8; b++) out[b * 128 + t] = acc[b] * invN + bb;
}

// ---------------- launcher ----------------

extern "C" void kernel_launch(void* const* d_in, const int* in_sizes, int n_in,
                              void* d_out, int out_size, void* d_ws, size_t ws_size,
                              hipStream_t stream) {
    const float* gene = (const float*)d_in[0];
    const float* W1   = (const float*)d_in[1];
    const float* b1   = (const float*)d_in[2];
    const float* W2   = (const float*)d_in[3];
    const float* b2   = (const float*)d_in[4];
    const int*   gid  = (const int*)d_in[5];
    const int*   eidx = (const int*)d_in[6];
    int N = in_sizes[5];
    int E = in_sizes[6] / 2;
    const int* src = eidx;
    const int* dst = eidx + E;
    float* out = (float*)d_out;

    char* p = (char*)d_ws;
    auto alloc = [&](size_t bytes) -> char* {
        char* r = p; p += (bytes + 255) & ~(size_t)255; return r;
    };
    float* deg    = (float*)alloc((size_t)N * 4);
    float* dinv   = (float*)alloc((size_t)N * 4);
    float* cval   = (float*)alloc((size_t)N * 4);
    float* wself  = (float*)alloc((size_t)N * 4);
    int*   indeg  = (int*)  alloc((size_t)N * 4);
    int*   offs   = (int*)  alloc((size_t)N * 4);
    int*   cursor = (int*)  alloc((size_t)N * 4);
    int*   bsums  = (int*)  alloc(256 * 4);
    int2*  csr    = (int2*) alloc((size_t)E * 8);
    float* s_acc  = (float*)alloc(1024 * 4);
    ushort* h2    = (ushort*)alloc((size_t)NG * BB * FD * 2);   // 41 MB, bf16 [b][g][j]

    int nb = (N + 255) / 256;   // 196 (must be <= 256 for scan2)
    int eb = (E + 255) / 256;

    const int NBLK = 2048;                 // 256 blocks/batch * 8 waves = 2048 waves per batch
    int wavesPerBatch = (NBLK / 8) * 8;
    int npw = (N + wavesPerBatch - 1) / wavesPerBatch;   // contiguous nodes per wave

    k_init <<<nb, 256, 0, stream>>>(deg, cursor, s_acc, N);
    k_count<<<eb, 256, 0, stream>>>(dst, deg, E);
    k_node <<<nb, 256, 0, stream>>>(deg, dinv, cval, wself, indeg, N);
    k_scan1<<<nb, 256, 0, stream>>>(indeg, offs, bsums, N);
    k_scan2<<<1, 256, 0, stream>>>(bsums, nb);
    k_scan3<<<nb, 256, 0, stream>>>(offs, bsums, N);
    k_fill <<<eb, 256, 0, stream>>>(src, dst, gid, dinv, cval, offs, cursor, csr, E);
    k_h    <<<NG / 8, 512, 0, stream>>>(gene, W1, h2);
    k_aggs <<<NBLK, 512, 0, stream>>>((const uint*)h2, gid, wself, csr, offs, indeg,
                                      cval, b1, s_acc, N, npw);
    k_final<<<1, 128, 0, stream>>>(s_acc, W2, b2, out, 1.0f / (float)N);
}

// Round 6
// 332.739 us; speedup vs baseline: 2.6737x; 1.2989x over previous
//
#include <hip/hip_runtime.h>

#define NG 20000   // NUM_GENES
#define BB 8       // batch
#define FD 128     // feature dim

typedef unsigned int uint;
typedef unsigned short ushort;
typedef __attribute__((ext_vector_type(8))) short short8v;
typedef __attribute__((ext_vector_type(4))) float float4v;

// ---------------- small setup kernels ----------------

__global__ void k_init(float* deg, float* s_acc, int N) {
    int i = blockIdx.x * blockDim.x + threadIdx.x;
    if (i < N) deg[i] = 1.0f;
    if (i < BB * FD) s_acc[i] = 0.0f;
}

__global__ void k_zero(int4* p, int n4) {
    int i = blockIdx.x * blockDim.x + threadIdx.x;
    if (i < n4) p[i] = make_int4(0, 0, 0, 0);
}

__global__ void k_count(const int* __restrict__ dst, float* deg, int E) {
    int e = blockIdx.x * blockDim.x + threadIdx.x;
    if (e < E) atomicAdd(&deg[dst[e]], 1.0f);
}

__global__ void k_node(const float* __restrict__ deg, float* dinv, float* cval,
                       float* wself, int* padcnt, int N) {
    int i = blockIdx.x * blockDim.x + threadIdx.x;
    if (i < N) {
        float d = deg[i];
        dinv[i]  = rsqrtf(d);
        float iv = 1.0f / d;
        cval[i]  = iv;                  // self-loop contribution to c[i]
        wself[i] = iv;                  // dinv^2 for the self term
        int nv = (int)d;                // in-edges + self
        padcnt[i] = (nv + 7) & ~7;      // pad to multiple of 8
    }
}

// exclusive scan of padcnt -> offs (2-level, blockDim must be 256)
__global__ void k_scan1(const int* __restrict__ padcnt, int* offs, int* bsums, int N) {
    __shared__ int sd[256];
    int t = threadIdx.x, idx = blockIdx.x * 256 + t;
    int v = (idx < N) ? padcnt[idx] : 0;
    sd[t] = v; __syncthreads();
    for (int o = 1; o < 256; o <<= 1) {
        int x = (t >= o) ? sd[t - o] : 0;
        __syncthreads();
        sd[t] += x;
        __syncthreads();
    }
    if (idx < N) offs[idx] = sd[t] - v;
    if (t == 255) bsums[blockIdx.x] = sd[255];
}

__global__ void k_scan2(int* bsums, int nb) {
    __shared__ int sd[256];
    int t = threadIdx.x;
    int v = (t < nb) ? bsums[t] : 0;
    sd[t] = v; __syncthreads();
    for (int o = 1; o < 256; o <<= 1) {
        int x = (t >= o) ? sd[t - o] : 0;
        __syncthreads();
        sd[t] += x;
        __syncthreads();
    }
    if (t < nb) bsums[t] = sd[t] - v;   // exclusive
}

__global__ void k_scan3(int* offs, const int* __restrict__ bsums, int N) {
    int i = blockIdx.x * blockDim.x + threadIdx.x;
    if (i < N) offs[i] += bsums[blockIdx.x];  // blockDim==256 so i>>8==blockIdx
}

// write the self-loop entry at slot 0 of each node's segment; cursor starts at 1
__global__ void k_self(const int* __restrict__ gid, const float* __restrict__ wself,
                       const int* __restrict__ offs, int* cursor, int2* csr, int N) {
    int i = blockIdx.x * blockDim.x + threadIdx.x;
    if (i < N) {
        csr[offs[i]] = make_int2(gid[i], __float_as_int(wself[i]));
        cursor[i] = 1;
    }
}

// build CSR by dst; also accumulate c[src] += norm. csr entry: {gene_row(src), norm bits}
__global__ void k_fill(const int* __restrict__ src, const int* __restrict__ dst,
                       const int* __restrict__ gid, const float* __restrict__ dinv,
                       float* cval, const int* __restrict__ offs, int* cursor,
                       int2* csr, int E) {
    int e = blockIdx.x * blockDim.x + threadIdx.x;
    if (e >= E) return;
    int s = src[e], d = dst[e];
    float nrm = dinv[s] * dinv[d];
    atomicAdd(&cval[s], nrm);
    int pos = atomicAdd(&cursor[d], 1);
    csr[offs[d] + pos] = make_int2(gid[s], __float_as_int(nrm));
}

// ---------------- bf16 helpers ----------------
__device__ __forceinline__ ushort f2bf(float x) {
    uint u = __float_as_uint(x);
    u += 0x7FFFu + ((u >> 16) & 1u);   // round to nearest even
    return (ushort)(u >> 16);
}
__device__ __forceinline__ float bf_lo(uint u) { return __uint_as_float(u << 16); }
__device__ __forceinline__ float bf_hi(uint u) { return __uint_as_float(u & 0xFFFF0000u); }

// W1 fp32 [k][j] -> w1t bf16 [j][k]  (tiny, one-time)
__global__ void k_w1t(const float* __restrict__ W1, ushort* __restrict__ w1t) {
    int j = blockIdx.x, k = threadIdx.x;   // 128 x 128
    w1t[j * 128 + k] = f2bf(W1[k * 128 + j]);
}

// ---------------- h = gene @ W1 via MFMA, bf16, batch-major flat rows ----------------
// gene is [b][g][128] fp32 = flat [160000][128]; h2 same flat layout bf16.
// Block 256 thr = 4 waves; tile M=64 (16 rows/wave), N=128, K=128 (single K-tile).
// LDS XOR-swizzle (G4): byte ^= ((row&7)<<4) kills the stride-256B bank conflict.
__global__ __launch_bounds__(256, 3)
void k_h(const float* __restrict__ gene, const ushort* __restrict__ w1t,
         ushort* __restrict__ h2) {
    __shared__ ushort Al[64 * 128];    // 16 KB  [row][k] swizzled
    __shared__ ushort Bl[128 * 128];   // 32 KB  [j][k]  swizzled
    int t = threadIdx.x;
    size_t row0 = (size_t)blockIdx.x * 64;

    // stage A: 64 rows x 128 k fp32 -> bf16 (ushort4 chunks: 32 chunks/row)
#pragma unroll
    for (int s = 0; s < 8; s++) {
        int f = t + s * 256;            // float4 index 0..2047
        int r = f >> 5, k0 = (f & 31) * 4;
        float4 v = *(const float4*)(gene + (row0 + r) * 128 + k0);
        ushort4 u;
        u.x = f2bf(v.x); u.y = f2bf(v.y); u.z = f2bf(v.z); u.w = f2bf(v.w);
        int byte = (r * 256 + k0 * 2) ^ ((r & 7) << 4);
        *(ushort4*)((char*)Al + byte) = u;
    }
    // stage B: 128x128 bf16 copy (16B chunks: 16 chunks per 128-ushort row)
#pragma unroll
    for (int s = 0; s < 8; s++) {
        int f = t + s * 256;            // 16B-chunk index 0..2047
        int j = f >> 4, k0 = (f & 15) * 8;     // FIX (R5 bug): was f>>3 / (f&7)*8 -> LDS OOB
        uint4 v = *(const uint4*)(w1t + j * 128 + k0);
        int byte = (j * 256 + k0 * 2) ^ ((j & 7) << 4);
        *(uint4*)((char*)Bl + byte) = v;
    }
    __syncthreads();

    int wid = t >> 6, lane = t & 63;
    int r0 = wid * 16;
    int lrow = lane & 15, lhi = lane >> 4;
    float4v acc[8];
#pragma unroll
    for (int nf = 0; nf < 8; nf++) acc[nf] = (float4v)(0.f);

#pragma unroll
    for (int c = 0; c < 4; c++) {
        int ra = r0 + lrow;
        int byteA = (ra * 256 + (c * 32 + lhi * 8) * 2) ^ ((ra & 7) << 4);
        short8v a = *(short8v*)((char*)Al + byteA);
#pragma unroll
        for (int nf = 0; nf < 8; nf++) {
            int jb = nf * 16 + lrow;
            int byteB = (jb * 256 + (c * 32 + lhi * 8) * 2) ^ ((jb & 7) << 4);
            short8v b = *(short8v*)((char*)Bl + byteB);
            acc[nf] = __builtin_amdgcn_mfma_f32_16x16x32_bf16(a, b, acc[nf], 0, 0, 0);
        }
    }
    // C/D: col = lane&15, row = (lane>>4)*4 + q  (m89/m91-verified)
#pragma unroll
    for (int nf = 0; nf < 8; nf++) {
#pragma unroll
        for (int q = 0; q < 4; q++) {
            int rr = lhi * 4 + q;
            int cc = nf * 16 + lrow;
            h2[(row0 + r0 + rr) * 128 + cc] = f2bf(acc[nf][q]);
        }
    }
}

// ---------------- fused gather + relu + weighted reduce (padded scalarized CSR) ----------------
// blockIdx % 8 = batch (round-robin blockIdx->XCD keeps each XCD on one 10.25MB table).
// Each wave owns contiguous nodes; bookkeeping is wave-uniform (SGPR/s_load); every node's
// segment (self + in-edges, zero-padded) is a multiple of 8 -> no serial tail, 8 gathers in flight.
__global__ __launch_bounds__(512)
void k_aggs(const uint* __restrict__ hb, const int2* __restrict__ csr,
            const int* __restrict__ offs, const int* __restrict__ padcnt,
            const float* __restrict__ cval, const float* __restrict__ b1,
            float* __restrict__ s_acc, int N, int npw) {
    int b    = blockIdx.x & 7;
    int wid  = threadIdx.x >> 6, lane = threadIdx.x & 63;
    int w    = __builtin_amdgcn_readfirstlane((blockIdx.x >> 3) * 8 + wid);
    const uint* base = hb + (size_t)b * NG * 64;   // this batch's table (scalar base)
    int j = lane * 2;
    float bx = b1[j], by = b1[j + 1];
    float sx = 0.f, sy = 0.f;

    int i0 = w * npw;
    int i1 = min(N, i0 + npw);
    for (int i = i0; i < i1; ++i) {
        int   e  = offs[i];
        int   pc = padcnt[i];
        float cv = cval[i];
        float ax = 0.f, ay = 0.f;
        for (int q = 0; q < pc; q += 8) {
            int ee = e + q;
            int2 c0 = csr[ee],     c1 = csr[ee + 1], c2 = csr[ee + 2], c3 = csr[ee + 3];
            int2 c4 = csr[ee + 4], c5 = csr[ee + 5], c6 = csr[ee + 6], c7 = csr[ee + 7];
            uint u0 = base[(size_t)c0.x * 64 + lane];
            uint u1 = base[(size_t)c1.x * 64 + lane];
            uint u2 = base[(size_t)c2.x * 64 + lane];
            uint u3 = base[(size_t)c3.x * 64 + lane];
            uint u4 = base[(size_t)c4.x * 64 + lane];
            uint u5 = base[(size_t)c5.x * 64 + lane];
            uint u6 = base[(size_t)c6.x * 64 + lane];
            uint u7 = base[(size_t)c7.x * 64 + lane];
            float n0 = __int_as_float(c0.y), n1 = __int_as_float(c1.y);
            float n2 = __int_as_float(c2.y), n3 = __int_as_float(c3.y);
            float n4 = __int_as_float(c4.y), n5 = __int_as_float(c5.y);
            float n6 = __int_as_float(c6.y), n7 = __int_as_float(c7.y);
            ax = fmaf(n0, bf_lo(u0), ax); ay = fmaf(n0, bf_hi(u0), ay);
            ax = fmaf(n1, bf_lo(u1), ax); ay = fmaf(n1, bf_hi(u1), ay);
            ax = fmaf(n2, bf_lo(u2), ax); ay = fmaf(n2, bf_hi(u2), ay);
            ax = fmaf(n3, bf_lo(u3), ax); ay = fmaf(n3, bf_hi(u3), ay);
            ax = fmaf(n4, bf_lo(u4), ax); ay = fmaf(n4, bf_hi(u4), ay);
            ax = fmaf(n5, bf_lo(u5), ax); ay = fmaf(n5, bf_hi(u5), ay);
            ax = fmaf(n6, bf_lo(u6), ax); ay = fmaf(n6, bf_hi(u6), ay);
            ax = fmaf(n7, bf_lo(u7), ax); ay = fmaf(n7, bf_hi(u7), ay);
        }
        sx += cv * fmaxf(ax + bx, 0.f);
        sy += cv * fmaxf(ay + by, 0.f);
    }

    // block-level reduction: 8 waves (same batch) -> 128 floats -> 1 atomic each
    __shared__ float red[8][128];
    red[wid][j]     = sx;
    red[wid][j + 1] = sy;
    __syncthreads();
    int t = threadIdx.x;
    if (t < 128) {
        float s = 0.f;
#pragma unroll
        for (int wv = 0; wv < 8; wv++) s += red[wv][t];
        atomicAdd(&s_acc[b * 128 + t], s);
    }
}

// out[b][j] = (s[b] @ W2)[j] / N + b2[j]   (tiny: 8x128x128)
__global__ void k_final(const float* __restrict__ s_acc, const float* __restrict__ W2,
                        const float* __restrict__ b2, float* __restrict__ out, float invN) {
    __shared__ float ss[1024];
    int t = threadIdx.x;  // 128 threads
    for (int idx = t; idx < 1024; idx += 128) ss[idx] = s_acc[idx];
    __syncthreads();
    float acc[8];
#pragma unroll
    for (int b = 0; b < 8; b++) acc[b] = 0.f;
    for (int k = 0; k < 128; k++) {
        float w = W2[k * 128 + t];
#pragma unroll
        for (int b = 0; b < 8; b++) acc[b] += ss[b * 128 + k] * w;
    }
    float bb = b2[t];
#pragma unroll
    for (int b = 0; b < 8; b++) out[b * 128 + t] = acc[b] * invN + bb;
}

// ---------------- launcher ----------------

extern "C" void kernel_launch(void* const* d_in, const int* in_sizes, int n_in,
                              void* d_out, int out_size, void* d_ws, size_t ws_size,
                              hipStream_t stream) {
    const float* gene = (const float*)d_in[0];
    const float* W1   = (const float*)d_in[1];
    const float* b1   = (const float*)d_in[2];
    const float* W2   = (const float*)d_in[3];
    const float* b2   = (const float*)d_in[4];
    const int*   gid  = (const int*)d_in[5];
    const int*   eidx = (const int*)d_in[6];
    int N = in_sizes[5];
    int E = in_sizes[6] / 2;
    const int* src = eidx;
    const int* dst = eidx + E;
    float* out = (float*)d_out;

    char* p = (char*)d_ws;
    auto alloc = [&](size_t bytes) -> char* {
        char* r = p; p += (bytes + 255) & ~(size_t)255; return r;
    };
    size_t csr_cap = (size_t)E + 8 * (size_t)N;          // padded upper bound (entries)
    float* deg    = (float*)alloc((size_t)N * 4);
    float* dinv   = (float*)alloc((size_t)N * 4);
    float* cval   = (float*)alloc((size_t)N * 4);
    float* wself  = (float*)alloc((size_t)N * 4);
    int*   padcnt = (int*)  alloc((size_t)N * 4);
    int*   offs   = (int*)  alloc((size_t)N * 4);
    int*   cursor = (int*)  alloc((size_t)N * 4);
    int*   bsums  = (int*)  alloc(256 * 4);
    int2*  csr    = (int2*) alloc(csr_cap * 8);
    float* s_acc  = (float*)alloc(1024 * 4);
    ushort* h2    = (ushort*)alloc((size_t)NG * BB * FD * 2);   // 41 MB, bf16 [b][g][j]
    ushort* w1t   = (ushort*)alloc(128 * 128 * 2);              // bf16 W1^T [j][k]

    int nb = (N + 255) / 256;   // 196 (must be <= 256 for scan2)
    int eb = (E + 255) / 256;
    int zn4 = (int)(csr_cap * 8 / 16);                   // int4 count to zero
    int zb  = (zn4 + 255) / 256;

    const int NBLK = 2048;                 // 256 blocks/batch * 8 waves = 2048 waves per batch
    int wavesPerBatch = (NBLK / 8) * 8;
    int npw = (N + wavesPerBatch - 1) / wavesPerBatch;   // contiguous nodes per wave

    k_init <<<nb, 256, 0, stream>>>(deg, s_acc, N);
    k_zero <<<zb, 256, 0, stream>>>((int4*)csr, zn4);
    k_w1t  <<<128, 128, 0, stream>>>(W1, w1t);
    k_count<<<eb, 256, 0, stream>>>(dst, deg, E);
    k_node <<<nb, 256, 0, stream>>>(deg, dinv, cval, wself, padcnt, N);
    k_scan1<<<nb, 256, 0, stream>>>(padcnt, offs, bsums, N);
    k_scan2<<<1, 256, 0, stream>>>(bsums, nb);
    k_scan3<<<nb, 256, 0, stream>>>(offs, bsums, N);
    k_self <<<nb, 256, 0, stream>>>(gid, wself, offs, cursor, csr, N);
    k_fill <<<eb, 256, 0, stream>>>(src, dst, gid, dinv, cval, offs, cursor, csr, E);
    k_h    <<<(NG * BB) / 64, 256, 0, stream>>>(gene, w1t, h2);
    k_aggs <<<NBLK, 512, 0, stream>>>((const uint*)h2, csr, offs, padcnt,
                                      cval, b1, s_acc, N, npw);
    k_final<<<1, 128, 0, stream>>>(s_acc, W2, b2, out, 1.0f / (float)N);
}

// Round 7
// 331.314 us; speedup vs baseline: 2.6852x; 1.0043x over previous
//
#include <hip/hip_runtime.h>

#define NG 20000   // NUM_GENES
#define BB 8       // batch
#define FD 128     // feature dim

typedef unsigned int uint;
typedef unsigned short ushort;
typedef __attribute__((ext_vector_type(8))) short short8v;
typedef __attribute__((ext_vector_type(4))) float float4v;

// ---------------- bf16 helpers ----------------
__device__ __forceinline__ ushort f2bf(float x) {
    uint u = __float_as_uint(x);
    u += 0x7FFFu + ((u >> 16) & 1u);   // round to nearest even
    return (ushort)(u >> 16);
}
__device__ __forceinline__ float bf_lo(uint u) { return __uint_as_float(u << 16); }
__device__ __forceinline__ float bf_hi(uint u) { return __uint_as_float(u & 0xFFFF0000u); }

// ---------------- fused setup: zero csr, init deg/s_acc, transpose W1 -> bf16 ----------------
__global__ void k_setup(int4* csrz, int zn4, float* deg, float* s_acc,
                        const float* __restrict__ W1, ushort* w1t, int N) {
    int i = blockIdx.x * blockDim.x + threadIdx.x;
    if (i < zn4) csrz[i] = make_int4(0, 0, 0, 0);
    if (i < N) deg[i] = 1.0f;
    if (i < BB * FD) s_acc[i] = 0.0f;
    if (i < FD * FD) {                      // w1t[j][k] = W1[k][j]
        int j = i >> 7, k = i & 127;
        w1t[i] = f2bf(W1[k * 128 + j]);
    }
}

__global__ void k_count(const int* __restrict__ dst, float* deg, int E) {
    int e = blockIdx.x * blockDim.x + threadIdx.x;
    if (e < E) atomicAdd(&deg[dst[e]], 1.0f);
}

// fused: per-node values + block-level exclusive scan of padcnt (blockDim must be 256)
__global__ void k_scanA(const float* __restrict__ deg, float* dinv, float* cval,
                        float* wself, int* padcnt, int* offs, int* bsums, int N) {
    __shared__ int sd[256];
    int t = threadIdx.x, idx = blockIdx.x * 256 + t;
    int v = 0;
    if (idx < N) {
        float d = deg[idx];
        dinv[idx]  = rsqrtf(d);
        float iv = 1.0f / d;
        cval[idx]  = iv;                // self-loop contribution to c[i]
        wself[idx] = iv;                // dinv^2 for the self term
        v = ((int)d + 7) & ~7;          // (in-edges + self) padded to mult of 8
        padcnt[idx] = v;
    }
    sd[t] = v; __syncthreads();
    for (int o = 1; o < 256; o <<= 1) {
        int x = (t >= o) ? sd[t - o] : 0;
        __syncthreads();
        sd[t] += x;
        __syncthreads();
    }
    if (idx < N) offs[idx] = sd[t] - v;
    if (t == 255) bsums[blockIdx.x] = sd[255];
}

__global__ void k_scan2(int* bsums, int nb) {
    __shared__ int sd[256];
    int t = threadIdx.x;
    int v = (t < nb) ? bsums[t] : 0;
    sd[t] = v; __syncthreads();
    for (int o = 1; o < 256; o <<= 1) {
        int x = (t >= o) ? sd[t - o] : 0;
        __syncthreads();
        sd[t] += x;
        __syncthreads();
    }
    if (t < nb) bsums[t] = sd[t] - v;   // exclusive
}

// fused: finalize offs + write self-loop entry at slot 0, cursor=1
__global__ void k_scanB(int* offs, const int* __restrict__ bsums,
                        const int* __restrict__ gid, const float* __restrict__ wself,
                        int* cursor, int2* csr, int N) {
    int i = blockIdx.x * blockDim.x + threadIdx.x;
    if (i < N) {
        int o = offs[i] + bsums[blockIdx.x];   // blockDim==256 so i>>8==blockIdx
        offs[i] = o;
        csr[o] = make_int2(gid[i], __float_as_int(wself[i]));
        cursor[i] = 1;
    }
}

// build CSR by dst; also accumulate c[src] += norm. csr entry: {gene_row(src), norm bits}
__global__ void k_fill(const int* __restrict__ src, const int* __restrict__ dst,
                       const int* __restrict__ gid, const float* __restrict__ dinv,
                       float* cval, const int* __restrict__ offs, int* cursor,
                       int2* csr, int E) {
    int e = blockIdx.x * blockDim.x + threadIdx.x;
    if (e >= E) return;
    int s = src[e], d = dst[e];
    float nrm = dinv[s] * dinv[d];
    atomicAdd(&cval[s], nrm);
    int pos = atomicAdd(&cursor[d], 1);
    csr[offs[d] + pos] = make_int2(gid[s], __float_as_int(nrm));
}

// ---------------- h = gene @ W1 via MFMA, bf16, PAIR-INTERLEAVED output ----------------
// gene: [b][g][128] fp32 = flat [160000][128].  Output: h2[pair][g][f][2] bf16
// (pair = b>>1, slot = b&1) so one dwordx2/lane serves 2 batches in the gather.
// Block 256 thr = 4 waves; tile M=64, N=128, K=128; LDS XOR-swizzle per G4.
__global__ __launch_bounds__(256, 3)
void k_h(const float* __restrict__ gene, const ushort* __restrict__ w1t,
         ushort* __restrict__ h2) {
    __shared__ ushort Al[64 * 128];    // 16 KB  [row][k] swizzled
    __shared__ ushort Bl[128 * 128];   // 32 KB  [j][k]  swizzled
    int t = threadIdx.x;
    size_t row0 = (size_t)blockIdx.x * 64;

    // stage A: 64 rows x 128 k fp32 -> bf16 (ushort4 chunks: 32 chunks/row)
#pragma unroll
    for (int s = 0; s < 8; s++) {
        int f = t + s * 256;            // float4 index 0..2047
        int r = f >> 5, k0 = (f & 31) * 4;
        float4 v = *(const float4*)(gene + (row0 + r) * 128 + k0);
        ushort4 u;
        u.x = f2bf(v.x); u.y = f2bf(v.y); u.z = f2bf(v.z); u.w = f2bf(v.w);
        int byte = (r * 256 + k0 * 2) ^ ((r & 7) << 4);
        *(ushort4*)((char*)Al + byte) = u;
    }
    // stage B: 128x128 bf16 copy (16B chunks: 16 chunks per 128-ushort row)
#pragma unroll
    for (int s = 0; s < 8; s++) {
        int f = t + s * 256;            // 16B-chunk index 0..2047
        int j = f >> 4, k0 = (f & 15) * 8;
        uint4 v = *(const uint4*)(w1t + j * 128 + k0);
        int byte = (j * 256 + k0 * 2) ^ ((j & 7) << 4);
        *(uint4*)((char*)Bl + byte) = v;
    }
    __syncthreads();

    int wid = t >> 6, lane = t & 63;
    int r0 = wid * 16;
    int lrow = lane & 15, lhi = lane >> 4;
    float4v acc[8];
#pragma unroll
    for (int nf = 0; nf < 8; nf++) acc[nf] = (float4v)(0.f);

#pragma unroll
    for (int c = 0; c < 4; c++) {
        int ra = r0 + lrow;
        int byteA = (ra * 256 + (c * 32 + lhi * 8) * 2) ^ ((ra & 7) << 4);
        short8v a = *(short8v*)((char*)Al + byteA);
#pragma unroll
        for (int nf = 0; nf < 8; nf++) {
            int jb = nf * 16 + lrow;
            int byteB = (jb * 256 + (c * 32 + lhi * 8) * 2) ^ ((jb & 7) << 4);
            short8v b = *(short8v*)((char*)Bl + byteB);
            acc[nf] = __builtin_amdgcn_mfma_f32_16x16x32_bf16(a, b, acc[nf], 0, 0, 0);
        }
    }
    // C/D: col = lane&15, row = (lane>>4)*4 + q  (m89/m91-verified)
#pragma unroll
    for (int nf = 0; nf < 8; nf++) {
#pragma unroll
        for (int q = 0; q < 4; q++) {
            int rr = lhi * 4 + q;
            int cc = nf * 16 + lrow;
            int rGlob = (int)row0 + r0 + rr;        // flat row = b*NG + g
            int bb = rGlob / NG;
            int gg = rGlob - bb * NG;
            size_t di = ((size_t)(bb >> 1) * NG + gg) * 256 + cc * 2 + (bb & 1);
            h2[di] = f2bf(acc[nf][q]);
        }
    }
}

// ---------------- fused gather + relu + weighted reduce (pair-interleaved, padded CSR) ----------------
// blockIdx & 3 = batch-pair; round-robin blockIdx->XCD puts pair p on XCDs p and p+4
// (20.5 MB table per pair). Wave owns contiguous nodes; bookkeeping wave-uniform (SGPR);
// one dwordx2/lane per entry serves both batches of the pair; 8 gathers in flight.
__global__ __launch_bounds__(512)
void k_aggp(const uint* __restrict__ hp, const int2* __restrict__ csr,
            const int* __restrict__ offs, const int* __restrict__ padcnt,
            const float* __restrict__ cval, const float* __restrict__ b1,
            float* __restrict__ s_acc, int N, int npw) {
    int p    = blockIdx.x & 3;
    int wid  = threadIdx.x >> 6, lane = threadIdx.x & 63;
    int w    = __builtin_amdgcn_readfirstlane((blockIdx.x >> 2) * 8 + wid);
    const uint* bp = hp + (size_t)p * NG * 128 + lane * 2;   // row = 128 uints (512 B)
    int l2 = lane * 2;
    float bx = b1[l2], by = b1[l2 + 1];
    float sx0 = 0.f, sx1 = 0.f, sy0 = 0.f, sy1 = 0.f;

    int i0 = w * npw;
    int i1 = min(N, i0 + npw);
    for (int i = i0; i < i1; ++i) {
        int   e  = offs[i];
        int   pc = padcnt[i];
        float cv = cval[i];
        float ax0 = 0.f, ax1 = 0.f, ay0 = 0.f, ay1 = 0.f;
        for (int q = 0; q < pc; q += 8) {
            int ee = e + q;
            int2 c0 = csr[ee],     c1 = csr[ee + 1], c2 = csr[ee + 2], c3 = csr[ee + 3];
            int2 c4 = csr[ee + 4], c5 = csr[ee + 5], c6 = csr[ee + 6], c7 = csr[ee + 7];
            uint2 u0 = *(const uint2*)(bp + (size_t)c0.x * 128);
            uint2 u1 = *(const uint2*)(bp + (size_t)c1.x * 128);
            uint2 u2 = *(const uint2*)(bp + (size_t)c2.x * 128);
            uint2 u3 = *(const uint2*)(bp + (size_t)c3.x * 128);
            uint2 u4 = *(const uint2*)(bp + (size_t)c4.x * 128);
            uint2 u5 = *(const uint2*)(bp + (size_t)c5.x * 128);
            uint2 u6 = *(const uint2*)(bp + (size_t)c6.x * 128);
            uint2 u7 = *(const uint2*)(bp + (size_t)c7.x * 128);
            float n0 = __int_as_float(c0.y), n1 = __int_as_float(c1.y);
            float n2 = __int_as_float(c2.y), n3 = __int_as_float(c3.y);
            float n4 = __int_as_float(c4.y), n5 = __int_as_float(c5.y);
            float n6 = __int_as_float(c6.y), n7 = __int_as_float(c7.y);
            ax0 = fmaf(n0, bf_lo(u0.x), ax0); ax1 = fmaf(n0, bf_hi(u0.x), ax1);
            ay0 = fmaf(n0, bf_lo(u0.y), ay0); ay1 = fmaf(n0, bf_hi(u0.y), ay1);
            ax0 = fmaf(n1, bf_lo(u1.x), ax0); ax1 = fmaf(n1, bf_hi(u1.x), ax1);
            ay0 = fmaf(n1, bf_lo(u1.y), ay0); ay1 = fmaf(n1, bf_hi(u1.y), ay1);
            ax0 = fmaf(n2, bf_lo(u2.x), ax0); ax1 = fmaf(n2, bf_hi(u2.x), ax1);
            ay0 = fmaf(n2, bf_lo(u2.y), ay0); ay1 = fmaf(n2, bf_hi(u2.y), ay1);
            ax0 = fmaf(n3, bf_lo(u3.x), ax0); ax1 = fmaf(n3, bf_hi(u3.x), ax1);
            ay0 = fmaf(n3, bf_lo(u3.y), ay0); ay1 = fmaf(n3, bf_hi(u3.y), ay1);
            ax0 = fmaf(n4, bf_lo(u4.x), ax0); ax1 = fmaf(n4, bf_hi(u4.x), ax1);
            ay0 = fmaf(n4, bf_lo(u4.y), ay0); ay1 = fmaf(n4, bf_hi(u4.y), ay1);
            ax0 = fmaf(n5, bf_lo(u5.x), ax0); ax1 = fmaf(n5, bf_hi(u5.x), ax1);
            ay0 = fmaf(n5, bf_lo(u5.y), ay0); ay1 = fmaf(n5, bf_hi(u5.y), ay1);
            ax0 = fmaf(n6, bf_lo(u6.x), ax0); ax1 = fmaf(n6, bf_hi(u6.x), ax1);
            ay0 = fmaf(n6, bf_lo(u6.y), ay0); ay1 = fmaf(n6, bf_hi(u6.y), ay1);
            ax0 = fmaf(n7, bf_lo(u7.x), ax0); ax1 = fmaf(n7, bf_hi(u7.x), ax1);
            ay0 = fmaf(n7, bf_lo(u7.y), ay0); ay1 = fmaf(n7, bf_hi(u7.y), ay1);
        }
        sx0 += cv * fmaxf(ax0 + bx, 0.f);
        sx1 += cv * fmaxf(ax1 + bx, 0.f);
        sy0 += cv * fmaxf(ay0 + by, 0.f);
        sy1 += cv * fmaxf(ay1 + by, 0.f);
    }

    // block reduce: 8 waves -> 256 sums (2 batches x 128 feats) -> 1 atomic each
    __shared__ float red[8][256];
    red[wid][lane * 4 + 0] = sx0;
    red[wid][lane * 4 + 1] = sx1;
    red[wid][lane * 4 + 2] = sy0;
    red[wid][lane * 4 + 3] = sy1;
    __syncthreads();
    int t = threadIdx.x;
    if (t < 256) {
        float s = 0.f;
#pragma unroll
        for (int wv = 0; wv < 8; wv++) s += red[wv][t];
        int l = t >> 2, c = t & 3;
        atomicAdd(&s_acc[(2 * p + (c & 1)) * 128 + 2 * l + (c >> 1)], s);
    }
}

// out[b][j] = (s[b] @ W2)[j] / N + b2[j]   (tiny: 8x128x128)
__global__ void k_final(const float* __restrict__ s_acc, const float* __restrict__ W2,
                        const float* __restrict__ b2, float* __restrict__ out, float invN) {
    __shared__ float ss[1024];
    int t = threadIdx.x;  // 128 threads
    for (int idx = t; idx < 1024; idx += 128) ss[idx] = s_acc[idx];
    __syncthreads();
    float acc[8];
#pragma unroll
    for (int b = 0; b < 8; b++) acc[b] = 0.f;
    for (int k = 0; k < 128; k++) {
        float w = W2[k * 128 + t];
#pragma unroll
        for (int b = 0; b < 8; b++) acc[b] += ss[b * 128 + k] * w;
    }
    float bb = b2[t];
#pragma unroll
    for (int b = 0; b < 8; b++) out[b * 128 + t] = acc[b] * invN + bb;
}

// ---------------- launcher ----------------

extern "C" void kernel_launch(void* const* d_in, const int* in_sizes, int n_in,
                              void* d_out, int out_size, void* d_ws, size_t ws_size,
                              hipStream_t stream) {
    const float* gene = (const float*)d_in[0];
    const float* W1   = (const float*)d_in[1];
    const float* b1   = (const float*)d_in[2];
    const float* W2   = (const float*)d_in[3];
    const float* b2   = (const float*)d_in[4];
    const int*   gid  = (const int*)d_in[5];
    const int*   eidx = (const int*)d_in[6];
    int N = in_sizes[5];
    int E = in_sizes[6] / 2;
    const int* src = eidx;
    const int* dst = eidx + E;
    float* out = (float*)d_out;

    char* p = (char*)d_ws;
    auto alloc = [&](size_t bytes) -> char* {
        char* r = p; p += (bytes + 255) & ~(size_t)255; return r;
    };
    size_t csr_cap = (size_t)E + 8 * (size_t)N;          // padded upper bound (entries)
    float* deg    = (float*)alloc((size_t)N * 4);
    float* dinv   = (float*)alloc((size_t)N * 4);
    float* cval   = (float*)alloc((size_t)N * 4);
    float* wself  = (float*)alloc((size_t)N * 4);
    int*   padcnt = (int*)  alloc((size_t)N * 4);
    int*   offs   = (int*)  alloc((size_t)N * 4);
    int*   cursor = (int*)  alloc((size_t)N * 4);
    int*   bsums  = (int*)  alloc(256 * 4);
    int2*  csr    = (int2*) alloc(csr_cap * 8);
    float* s_acc  = (float*)alloc(1024 * 4);
    ushort* h2    = (ushort*)alloc((size_t)NG * BB * FD * 2);   // 41 MB, bf16 [pair][g][f][2]
    ushort* w1t   = (ushort*)alloc(128 * 128 * 2);              // bf16 W1^T [j][k]

    int nb = (N + 255) / 256;   // 196 (must be <= 256 for scan2)
    int eb = (E + 255) / 256;
    int zn4 = (int)(csr_cap * 8 / 16);                   // int4 count to zero
    int zb  = (zn4 + 255) / 256;

    const int NBLK = 2048;                 // 512 blocks/pair * 8 waves = 4096 waves per pair
    int wavesPerPair = (NBLK / 4) * 8;
    int npw = (N + wavesPerPair - 1) / wavesPerPair;     // contiguous nodes per wave

    k_setup<<<zb, 256, 0, stream>>>((int4*)csr, zn4, deg, s_acc, W1, w1t, N);
    k_count<<<eb, 256, 0, stream>>>(dst, deg, E);
    k_scanA<<<nb, 256, 0, stream>>>(deg, dinv, cval, wself, padcnt, offs, bsums, N);
    k_scan2<<<1, 256, 0, stream>>>(bsums, nb);
    k_scanB<<<nb, 256, 0, stream>>>(offs, bsums, gid, wself, cursor, csr, N);
    k_fill <<<eb, 256, 0, stream>>>(src, dst, gid, dinv, cval, offs, cursor, csr, E);
    k_h    <<<(NG * BB) / 64, 256, 0, stream>>>(gene, w1t, h2);
    k_aggp <<<NBLK, 512, 0, stream>>>((const uint*)h2, csr, offs, padcnt,
                                      cval, b1, s_acc, N, npw);
    k_final<<<1, 128, 0, stream>>>(s_acc, W2, b2, out, 1.0f / (float)N);
}

// Round 8
// 322.682 us; speedup vs baseline: 2.7570x; 1.0268x over previous
//
#include <hip/hip_runtime.h>

#define NG 20000   // NUM_GENES
#define BB 8       // batch
#define FD 128     // feature dim

typedef unsigned int uint;
typedef unsigned short ushort;
typedef __attribute__((ext_vector_type(8))) short short8v;
typedef __attribute__((ext_vector_type(4))) float float4v;
typedef __attribute__((ext_vector_type(4))) int int4v;
typedef __attribute__((ext_vector_type(2))) float f2v;

// raw buffer load, CK-style intrinsic binding; aux=1 -> GLC -> sc0 on gfx950 (L1 bypass, L2 fills)
__device__ f2v llvm_rbl_v2f32(int4v srsrc, int voffset, int soffset, int aux)
    __asm("llvm.amdgcn.raw.buffer.load.v2f32");

__device__ __forceinline__ int4v make_srsrc(const void* p) {
    int4v r;
    r.x = (int)(uint)(uintptr_t)p;
    r.y = (int)(uint)((uintptr_t)p >> 32);
    r.z = -1;              // num_records = 0xFFFFFFFF -> bounds check disabled
    r.w = 0x00020000;      // raw untyped dword access
    return r;
}

// ---------------- bf16 helpers ----------------
__device__ __forceinline__ ushort f2bf(float x) {
    uint u = __float_as_uint(x);
    u += 0x7FFFu + ((u >> 16) & 1u);   // round to nearest even
    return (ushort)(u >> 16);
}
__device__ __forceinline__ float bf_lo(uint u) { return __uint_as_float(u << 16); }
__device__ __forceinline__ float bf_hi(uint u) { return __uint_as_float(u & 0xFFFF0000u); }

// ---------------- fused setup: zero csr, init deg/s_acc, transpose W1 -> bf16 ----------------
__global__ void k_setup(int4* csrz, int zn4, float* deg, float* s_acc,
                        const float* __restrict__ W1, ushort* w1t, int N) {
    int i = blockIdx.x * blockDim.x + threadIdx.x;
    if (i < zn4) csrz[i] = make_int4(0, 0, 0, 0);
    if (i < N) deg[i] = 1.0f;
    if (i < BB * FD) s_acc[i] = 0.0f;
    if (i < FD * FD) {                      // w1t[j][k] = W1[k][j]
        int j = i >> 7, k = i & 127;
        w1t[i] = f2bf(W1[k * 128 + j]);
    }
}

__global__ void k_count(const int* __restrict__ dst, float* deg, int E) {
    int e = blockIdx.x * blockDim.x + threadIdx.x;
    if (e < E) atomicAdd(&deg[dst[e]], 1.0f);
}

// fused: per-node values + block-level exclusive scan of padcnt (blockDim must be 256)
__global__ void k_scanA(const float* __restrict__ deg, float* dinv, float* cval,
                        float* wself, int* padcnt, int* offs, int* bsums, int N) {
    __shared__ int sd[256];
    int t = threadIdx.x, idx = blockIdx.x * 256 + t;
    int v = 0;
    if (idx < N) {
        float d = deg[idx];
        dinv[idx]  = rsqrtf(d);
        float iv = 1.0f / d;
        cval[idx]  = iv;                // self-loop contribution to c[i]
        wself[idx] = iv;                // dinv^2 for the self term
        v = ((int)d + 7) & ~7;          // (in-edges + self) padded to mult of 8
        padcnt[idx] = v;
    }
    sd[t] = v; __syncthreads();
    for (int o = 1; o < 256; o <<= 1) {
        int x = (t >= o) ? sd[t - o] : 0;
        __syncthreads();
        sd[t] += x;
        __syncthreads();
    }
    if (idx < N) offs[idx] = sd[t] - v;
    if (t == 255) bsums[blockIdx.x] = sd[255];
}

__global__ void k_scan2(int* bsums, int nb) {
    __shared__ int sd[256];
    int t = threadIdx.x;
    int v = (t < nb) ? bsums[t] : 0;
    sd[t] = v; __syncthreads();
    for (int o = 1; o < 256; o <<= 1) {
        int x = (t >= o) ? sd[t - o] : 0;
        __syncthreads();
        sd[t] += x;
        __syncthreads();
    }
    if (t < nb) bsums[t] = sd[t] - v;   // exclusive
}

// fused: finalize offs + write self-loop entry at slot 0, cursor=1
__global__ void k_scanB(int* offs, const int* __restrict__ bsums,
                        const int* __restrict__ gid, const float* __restrict__ wself,
                        int* cursor, int2* csr, int N) {
    int i = blockIdx.x * blockDim.x + threadIdx.x;
    if (i < N) {
        int o = offs[i] + bsums[blockIdx.x];   // blockDim==256 so i>>8==blockIdx
        offs[i] = o;
        csr[o] = make_int2(gid[i], __float_as_int(wself[i]));
        cursor[i] = 1;
    }
}

// build CSR by dst; also accumulate c[src] += norm. csr entry: {gene_row(src), norm bits}
__global__ void k_fill(const int* __restrict__ src, const int* __restrict__ dst,
                       const int* __restrict__ gid, const float* __restrict__ dinv,
                       float* cval, const int* __restrict__ offs, int* cursor,
                       int2* csr, int E) {
    int e = blockIdx.x * blockDim.x + threadIdx.x;
    if (e >= E) return;
    int s = src[e], d = dst[e];
    float nrm = dinv[s] * dinv[d];
    atomicAdd(&cval[s], nrm);
    int pos = atomicAdd(&cursor[d], 1);
    csr[offs[d] + pos] = make_int2(gid[s], __float_as_int(nrm));
}

// ---------------- h = gene @ W1 via MFMA; block = (pair, 32-gene tile) ----------------
// Both batches of a pair computed in-block -> pair-interleaved output written as
// COALESCED dword stores (was: 41 MB of strided 2-byte scatter).
// LDS: Al 16KB (A swizzled) + Bl 32KB (B swizzled); reused as Cl (fp32 64x128) post-MFMA.
__global__ __launch_bounds__(256, 3)
void k_h(const float* __restrict__ gene, const ushort* __restrict__ w1t,
         uint* __restrict__ h2u) {
    __shared__ __align__(16) char smem[49152];
    ushort* Al = (ushort*)smem;            // [64][128] bf16, row = gi*? see below
    ushort* Bl = (ushort*)(smem + 16384);  // [128][128] bf16
    float*  Cl = (float*)smem;             // [64][128] fp32 (reuse after MFMA)
    int t = threadIdx.x;
    int p    = blockIdx.x & 3;             // batch pair
    int tile = blockIdx.x >> 2;
    int g0   = tile * 32;

    // stage A: rows 0..31 = batch 2p genes g0..g0+31; rows 32..63 = batch 2p+1
#pragma unroll
    for (int s = 0; s < 8; s++) {
        int f = t + s * 256;            // float4 index 0..2047
        int r = f >> 5, k0 = (f & 31) * 4;
        int bb = 2 * p + (r >> 5);
        int gg = g0 + (r & 31);
        float4 v = *(const float4*)(gene + ((size_t)bb * NG + gg) * 128 + k0);
        ushort4 u;
        u.x = f2bf(v.x); u.y = f2bf(v.y); u.z = f2bf(v.z); u.w = f2bf(v.w);
        int byte = (r * 256 + k0 * 2) ^ ((r & 7) << 4);
        *(ushort4*)((char*)Al + byte) = u;
    }
    // stage B: 128x128 bf16 copy (16B chunks: 16 per 128-ushort row)
#pragma unroll
    for (int s = 0; s < 8; s++) {
        int f = t + s * 256;
        int j = f >> 4, k0 = (f & 15) * 8;
        uint4 v = *(const uint4*)(w1t + j * 128 + k0);
        int byte = (j * 256 + k0 * 2) ^ ((j & 7) << 4);
        *(uint4*)((char*)Bl + byte) = v;
    }
    __syncthreads();

    int wid = t >> 6, lane = t & 63;
    int r0 = wid * 16;
    int lrow = lane & 15, lhi = lane >> 4;
    float4v acc[8];
#pragma unroll
    for (int nf = 0; nf < 8; nf++) acc[nf] = (float4v)(0.f);

#pragma unroll
    for (int c = 0; c < 4; c++) {
        int ra = r0 + lrow;
        int byteA = (ra * 256 + (c * 32 + lhi * 8) * 2) ^ ((ra & 7) << 4);
        short8v a = *(short8v*)((char*)Al + byteA);
#pragma unroll
        for (int nf = 0; nf < 8; nf++) {
            int jb = nf * 16 + lrow;
            int byteB = (jb * 256 + (c * 32 + lhi * 8) * 2) ^ ((jb & 7) << 4);
            short8v b = *(short8v*)((char*)Bl + byteB);
            acc[nf] = __builtin_amdgcn_mfma_f32_16x16x32_bf16(a, b, acc[nf], 0, 0, 0);
        }
    }
    __syncthreads();   // Al/Bl dead; reuse as Cl

    // C/D: col = lane&15, row = (lane>>4)*4 + q
#pragma unroll
    for (int nf = 0; nf < 8; nf++) {
#pragma unroll
        for (int q = 0; q < 4; q++) {
            Cl[(r0 + lhi * 4 + q) * 128 + nf * 16 + lrow] = acc[nf][q];
        }
    }
    __syncthreads();

    // pack pairs -> coalesced uint stores: h2u[(p*NG + g)*128 + cc] = {lo=batch2p, hi=batch2p+1}
#pragma unroll
    for (int s = 0; s < 16; s++) {
        int flat = t + s * 256;           // 0..4095
        int gi = flat >> 7, cc = flat & 127;
        float lo = Cl[gi * 128 + cc];
        float hi = Cl[(32 + gi) * 128 + cc];
        uint u = (uint)f2bf(lo) | ((uint)f2bf(hi) << 16);
        h2u[((size_t)p * NG + g0 + gi) * 128 + cc] = u;
    }
}

// ---------------- fused gather + relu + weighted reduce (pair-interleaved, padded CSR) ----------------
// blockIdx & 3 = batch-pair. Wave owns contiguous nodes; bookkeeping wave-uniform (SGPR);
// row gathers are buffer_load_dwordx2 with sc0 (L1 bypass — every access is an L1 miss anyway),
// soffset = SGPR row offset, voffset = lane*8. 8 gathers in flight.
__global__ __launch_bounds__(512)
void k_aggp(const uint* __restrict__ hp, const int2* __restrict__ csr,
            const int* __restrict__ offs, const int* __restrict__ padcnt,
            const float* __restrict__ cval, const float* __restrict__ b1,
            float* __restrict__ s_acc, int N, int npw) {
    int p    = blockIdx.x & 3;
    int wid  = threadIdx.x >> 6, lane = threadIdx.x & 63;
    int w    = __builtin_amdgcn_readfirstlane((blockIdx.x >> 2) * 8 + wid);
    int4v sr = make_srsrc(hp + (size_t)p * NG * 128);    // pair table base
    int voff = lane * 8;                                  // per-lane byte offset
    int l2 = lane * 2;
    float bx = b1[l2], by = b1[l2 + 1];
    float sx0 = 0.f, sx1 = 0.f, sy0 = 0.f, sy1 = 0.f;

    int i0 = w * npw;
    int i1 = min(N, i0 + npw);
    for (int i = i0; i < i1; ++i) {
        int   e  = offs[i];
        int   pc = padcnt[i];
        float cv = cval[i];
        float ax0 = 0.f, ax1 = 0.f, ay0 = 0.f, ay1 = 0.f;
        for (int q = 0; q < pc; q += 8) {
            int ee = e + q;
            int2 c0 = csr[ee],     c1 = csr[ee + 1], c2 = csr[ee + 2], c3 = csr[ee + 3];
            int2 c4 = csr[ee + 4], c5 = csr[ee + 5], c6 = csr[ee + 6], c7 = csr[ee + 7];
            f2v u0 = llvm_rbl_v2f32(sr, voff, c0.x << 9, 1);
            f2v u1 = llvm_rbl_v2f32(sr, voff, c1.x << 9, 1);
            f2v u2 = llvm_rbl_v2f32(sr, voff, c2.x << 9, 1);
            f2v u3 = llvm_rbl_v2f32(sr, voff, c3.x << 9, 1);
            f2v u4 = llvm_rbl_v2f32(sr, voff, c4.x << 9, 1);
            f2v u5 = llvm_rbl_v2f32(sr, voff, c5.x << 9, 1);
            f2v u6 = llvm_rbl_v2f32(sr, voff, c6.x << 9, 1);
            f2v u7 = llvm_rbl_v2f32(sr, voff, c7.x << 9, 1);
            float n0 = __int_as_float(c0.y), n1 = __int_as_float(c1.y);
            float n2 = __int_as_float(c2.y), n3 = __int_as_float(c3.y);
            float n4 = __int_as_float(c4.y), n5 = __int_as_float(c5.y);
            float n6 = __int_as_float(c6.y), n7 = __int_as_float(c7.y);
            uint a, b;
            a = __float_as_uint(u0.x); b = __float_as_uint(u0.y);
            ax0 = fmaf(n0, bf_lo(a), ax0); ax1 = fmaf(n0, bf_hi(a), ax1);
            ay0 = fmaf(n0, bf_lo(b), ay0); ay1 = fmaf(n0, bf_hi(b), ay1);
            a = __float_as_uint(u1.x); b = __float_as_uint(u1.y);
            ax0 = fmaf(n1, bf_lo(a), ax0); ax1 = fmaf(n1, bf_hi(a), ax1);
            ay0 = fmaf(n1, bf_lo(b), ay0); ay1 = fmaf(n1, bf_hi(b), ay1);
            a = __float_as_uint(u2.x); b = __float_as_uint(u2.y);
            ax0 = fmaf(n2, bf_lo(a), ax0); ax1 = fmaf(n2, bf_hi(a), ax1);
            ay0 = fmaf(n2, bf_lo(b), ay0); ay1 = fmaf(n2, bf_hi(b), ay1);
            a = __float_as_uint(u3.x); b = __float_as_uint(u3.y);
            ax0 = fmaf(n3, bf_lo(a), ax0); ax1 = fmaf(n3, bf_hi(a), ax1);
            ay0 = fmaf(n3, bf_lo(b), ay0); ay1 = fmaf(n3, bf_hi(b), ay1);
            a = __float_as_uint(u4.x); b = __float_as_uint(u4.y);
            ax0 = fmaf(n4, bf_lo(a), ax0); ax1 = fmaf(n4, bf_hi(a), ax1);
            ay0 = fmaf(n4, bf_lo(b), ay0); ay1 = fmaf(n4, bf_hi(b), ay1);
            a = __float_as_uint(u5.x); b = __float_as_uint(u5.y);
            ax0 = fmaf(n5, bf_lo(a), ax0); ax1 = fmaf(n5, bf_hi(a), ax1);
            ay0 = fmaf(n5, bf_lo(b), ay0); ay1 = fmaf(n5, bf_hi(b), ay1);
            a = __float_as_uint(u6.x); b = __float_as_uint(u6.y);
            ax0 = fmaf(n6, bf_lo(a), ax0); ax1 = fmaf(n6, bf_hi(a), ax1);
            ay0 = fmaf(n6, bf_lo(b), ay0); ay1 = fmaf(n6, bf_hi(b), ay1);
            a = __float_as_uint(u7.x); b = __float_as_uint(u7.y);
            ax0 = fmaf(n7, bf_lo(a), ax0); ax1 = fmaf(n7, bf_hi(a), ax1);
            ay0 = fmaf(n7, bf_lo(b), ay0); ay1 = fmaf(n7, bf_hi(b), ay1);
        }
        sx0 += cv * fmaxf(ax0 + bx, 0.f);
        sx1 += cv * fmaxf(ax1 + bx, 0.f);
        sy0 += cv * fmaxf(ay0 + by, 0.f);
        sy1 += cv * fmaxf(ay1 + by, 0.f);
    }

    // block reduce: 8 waves -> 256 sums (2 batches x 128 feats) -> 1 atomic each
    __shared__ float red[8][256];
    red[wid][lane * 4 + 0] = sx0;
    red[wid][lane * 4 + 1] = sx1;
    red[wid][lane * 4 + 2] = sy0;
    red[wid][lane * 4 + 3] = sy1;
    __syncthreads();
    int t = threadIdx.x;
    if (t < 256) {
        float s = 0.f;
#pragma unroll
        for (int wv = 0; wv < 8; wv++) s += red[wv][t];
        int l = t >> 2, c = t & 3;
        atomicAdd(&s_acc[(2 * p + (c & 1)) * 128 + 2 * l + (c >> 1)], s);
    }
}

// out[b][j] = (s[b] @ W2)[j] / N + b2[j]   (tiny: 8x128x128)
__global__ void k_final(const float* __restrict__ s_acc, const float* __restrict__ W2,
                        const float* __restrict__ b2, float* __restrict__ out, float invN) {
    __shared__ float ss[1024];
    int t = threadIdx.x;  // 128 threads
    for (int idx = t; idx < 1024; idx += 128) ss[idx] = s_acc[idx];
    __syncthreads();
    float acc[8];
#pragma unroll
    for (int b = 0; b < 8; b++) acc[b] = 0.f;
    for (int k = 0; k < 128; k++) {
        float w = W2[k * 128 + t];
#pragma unroll
        for (int b = 0; b < 8; b++) acc[b] += ss[b * 128 + k] * w;
    }
    float bb = b2[t];
#pragma unroll
    for (int b = 0; b < 8; b++) out[b * 128 + t] = acc[b] * invN + bb;
}

// ---------------- launcher ----------------

extern "C" void kernel_launch(void* const* d_in, const int* in_sizes, int n_in,
                              void* d_out, int out_size, void* d_ws, size_t ws_size,
                              hipStream_t stream) {
    const float* gene = (const float*)d_in[0];
    const float* W1   = (const float*)d_in[1];
    const float* b1   = (const float*)d_in[2];
    const float* W2   = (const float*)d_in[3];
    const float* b2   = (const float*)d_in[4];
    const int*   gid  = (const int*)d_in[5];
    const int*   eidx = (const int*)d_in[6];
    int N = in_sizes[5];
    int E = in_sizes[6] / 2;
    const int* src = eidx;
    const int* dst = eidx + E;
    float* out = (float*)d_out;

    char* p = (char*)d_ws;
    auto alloc = [&](size_t bytes) -> char* {
        char* r = p; p += (bytes + 255) & ~(size_t)255; return r;
    };
    size_t csr_cap = (size_t)E + 8 * (size_t)N;          // padded upper bound (entries)
    float* deg    = (float*)alloc((size_t)N * 4);
    float* dinv   = (float*)alloc((size_t)N * 4);
    float* cval   = (float*)alloc((size_t)N * 4);
    float* wself  = (float*)alloc((size_t)N * 4);
    int*   padcnt = (int*)  alloc((size_t)N * 4);
    int*   offs   = (int*)  alloc((size_t)N * 4);
    int*   cursor = (int*)  alloc((size_t)N * 4);
    int*   bsums  = (int*)  alloc(256 * 4);
    int2*  csr    = (int2*) alloc(csr_cap * 8);
    float* s_acc  = (float*)alloc(1024 * 4);
    uint*  h2     = (uint*) alloc((size_t)NG * BB * FD * 2);   // 41 MB, bf16 [pair][g][f][2]
    ushort* w1t   = (ushort*)alloc(128 * 128 * 2);             // bf16 W1^T [j][k]

    int nb = (N + 255) / 256;   // 196 (must be <= 256 for scan2)
    int eb = (E + 255) / 256;
    int zn4 = (int)(csr_cap * 8 / 16);                   // int4 count to zero
    int zb  = (zn4 + 255) / 256;

    const int NBLK = 2048;                 // 512 blocks/pair * 8 waves = 4096 waves per pair
    int wavesPerPair = (NBLK / 4) * 8;
    int npw = (N + wavesPerPair - 1) / wavesPerPair;     // contiguous nodes per wave

    k_setup<<<zb, 256, 0, stream>>>((int4*)csr, zn4, deg, s_acc, W1, w1t, N);
    k_count<<<eb, 256, 0, stream>>>(dst, deg, E);
    k_scanA<<<nb, 256, 0, stream>>>(deg, dinv, cval, wself, padcnt, offs, bsums, N);
    k_scan2<<<1, 256, 0, stream>>>(bsums, nb);
    k_scanB<<<nb, 256, 0, stream>>>(offs, bsums, gid, wself, cursor, csr, N);
    k_fill <<<eb, 256, 0, stream>>>(src, dst, gid, dinv, cval, offs, cursor, csr, E);
    k_h    <<<4 * (NG / 32), 256, 0, stream>>>(gene, w1t, h2);
    k_aggp <<<NBLK, 512, 0, stream>>>(h2, csr, offs, padcnt,
                                      cval, b1, s_acc, N, npw);
    k_final<<<1, 128, 0, stream>>>(s_acc, W2, b2, out, 1.0f / (float)N);
}

// Round 9
// 306.604 us; speedup vs baseline: 2.9016x; 1.0524x over previous
//
#include <hip/hip_runtime.h>

#define NG 20000   // NUM_GENES
#define BB 8       // batch
#define FD 128     // feature dim

typedef unsigned int uint;
typedef unsigned short ushort;
typedef __attribute__((ext_vector_type(8))) short short8v;
typedef __attribute__((ext_vector_type(4))) float float4v;
typedef __attribute__((ext_vector_type(4))) int int4v;
typedef __attribute__((ext_vector_type(2))) float f2v;

// raw buffer load (CK-style binding). aux=0: normal cached load.
__device__ f2v llvm_rbl_v2f32(int4v srsrc, int voffset, int soffset, int aux)
    __asm("llvm.amdgcn.raw.buffer.load.v2f32");

__device__ __forceinline__ int4v make_srsrc(const void* p) {
    int4v r;
    r.x = (int)(uint)(uintptr_t)p;
    r.y = (int)(uint)((uintptr_t)p >> 32);
    r.z = -1;              // num_records = 0xFFFFFFFF -> bounds check disabled
    r.w = 0x00020000;      // raw untyped dword access
    return r;
}

// ---------------- bf16 helpers ----------------
__device__ __forceinline__ ushort f2bf(float x) {
    uint u = __float_as_uint(x);
    u += 0x7FFFu + ((u >> 16) & 1u);   // round to nearest even
    return (ushort)(u >> 16);
}
__device__ __forceinline__ float bf_lo(uint u) { return __uint_as_float(u << 16); }
__device__ __forceinline__ float bf_hi(uint u) { return __uint_as_float(u & 0xFFFF0000u); }

// ---------------- fused setup: zero csr, zero ideg, init s_acc, transpose W1 -> bf16 ----------------
__global__ void k_setup(int4* csrz, int zn4, int* ideg, float* s_acc,
                        const float* __restrict__ W1, ushort* w1t, int N) {
    int i = blockIdx.x * blockDim.x + threadIdx.x;
    if (i < zn4) csrz[i] = make_int4(0, 0, 0, 0);
    if (i < N) ideg[i] = 0;
    if (i < BB * FD) s_acc[i] = 0.0f;
    if (i < FD * FD) {                      // w1t[j][k] = W1[k][j]
        int j = i >> 7, k = i & 127;
        w1t[i] = f2bf(W1[k * 128 + j]);
    }
}

__global__ void k_count(const int* __restrict__ dst, int* ideg, int E) {
    int e = blockIdx.x * blockDim.x + threadIdx.x;
    if (e < E) atomicAdd(&ideg[dst[e]], 1);
}

// fused: per-node values + block-level exclusive scan of padcnt (blockDim must be 256)
__global__ void k_scanA(const int* __restrict__ ideg, float* dinv, float* cval,
                        float* wself, int* padcnt, int* offs, int* bsums, int N) {
    __shared__ int sd[256];
    int t = threadIdx.x, idx = blockIdx.x * 256 + t;
    int v = 0;
    if (idx < N) {
        int d = ideg[idx] + 1;          // in-edges + self
        float fd = (float)d;
        dinv[idx]  = rsqrtf(fd);
        float iv = 1.0f / fd;
        cval[idx]  = iv;                // self-loop contribution to c[i]
        wself[idx] = iv;                // dinv^2 for the self term
        v = (d + 7) & ~7;               // padded to mult of 8
        padcnt[idx] = v;
    }
    sd[t] = v; __syncthreads();
    for (int o = 1; o < 256; o <<= 1) {
        int x = (t >= o) ? sd[t - o] : 0;
        __syncthreads();
        sd[t] += x;
        __syncthreads();
    }
    if (idx < N) offs[idx] = sd[t] - v;
    if (t == 255) bsums[blockIdx.x] = sd[255];
}

__global__ void k_scan2(int* bsums, int nb) {
    __shared__ int sd[256];
    int t = threadIdx.x;
    int v = (t < nb) ? bsums[t] : 0;
    sd[t] = v; __syncthreads();
    for (int o = 1; o < 256; o <<= 1) {
        int x = (t >= o) ? sd[t - o] : 0;
        __syncthreads();
        sd[t] += x;
        __syncthreads();
    }
    if (t < nb) bsums[t] = sd[t] - v;   // exclusive
}

// fused: finalize offs + write self-loop entry at slot 0, cursor=1
__global__ void k_scanB(int* offs, const int* __restrict__ bsums,
                        const int* __restrict__ gid, const float* __restrict__ wself,
                        int* cursor, int2* csr, int N) {
    int i = blockIdx.x * blockDim.x + threadIdx.x;
    if (i < N) {
        int o = offs[i] + bsums[blockIdx.x];   // blockDim==256 so i>>8==blockIdx
        offs[i] = o;
        csr[o] = make_int2(gid[i], __float_as_int(wself[i]));
        cursor[i] = 1;
    }
}

// ---------------- MERGED: CSR fill (blocks 0..eb-1)  ||  h = gene @ W1 MFMA (blocks eb..) ----------------
// fill and h are independent after scanB; co-residency hides fill's random-atomic latency
// under h's MFMA/streaming work.
__global__ __launch_bounds__(256, 3)
void k_fillh(const int* __restrict__ src, const int* __restrict__ dst,
             const int* __restrict__ gid, const float* __restrict__ dinv,
             float* cval, const int* __restrict__ offs, int* cursor,
             int2* csr, int E, int eb,
             const float* __restrict__ gene, const ushort* __restrict__ w1t,
             uint* __restrict__ h2u) {
    __shared__ __align__(16) char smem[49152];
    if ((int)blockIdx.x < eb) {
        // ---- CSR fill path ----
        int e = blockIdx.x * 256 + threadIdx.x;
        if (e >= E) return;
        int s = src[e], d = dst[e];
        float nrm = dinv[s] * dinv[d];
        atomicAdd(&cval[s], nrm);
        int pos = atomicAdd(&cursor[d], 1);
        csr[offs[d] + pos] = make_int2(gid[s], __float_as_int(nrm));
        return;
    }
    // ---- h path: block = (pair, 32-gene tile) ----
    ushort* Al = (ushort*)smem;            // [64][128] bf16 swizzled
    ushort* Bl = (ushort*)(smem + 16384);  // [128][128] bf16 swizzled
    float*  Cl = (float*)smem;             // [64][128] fp32 (reuse after MFMA)
    int t = threadIdx.x;
    int hb   = blockIdx.x - eb;
    int p    = hb & 3;                     // batch pair
    int tile = hb >> 2;
    int g0   = tile * 32;

    // stage A: rows 0..31 = batch 2p genes g0..g0+31; rows 32..63 = batch 2p+1
#pragma unroll
    for (int s = 0; s < 8; s++) {
        int f = t + s * 256;            // float4 index 0..2047
        int r = f >> 5, k0 = (f & 31) * 4;
        int bb = 2 * p + (r >> 5);
        int gg = g0 + (r & 31);
        float4 v = *(const float4*)(gene + ((size_t)bb * NG + gg) * 128 + k0);
        ushort4 u;
        u.x = f2bf(v.x); u.y = f2bf(v.y); u.z = f2bf(v.z); u.w = f2bf(v.w);
        int byte = (r * 256 + k0 * 2) ^ ((r & 7) << 4);
        *(ushort4*)((char*)Al + byte) = u;
    }
    // stage B: 128x128 bf16 copy (16B chunks: 16 per 128-ushort row)
#pragma unroll
    for (int s = 0; s < 8; s++) {
        int f = t + s * 256;
        int j = f >> 4, k0 = (f & 15) * 8;
        uint4 v = *(const uint4*)(w1t + j * 128 + k0);
        int byte = (j * 256 + k0 * 2) ^ ((j & 7) << 4);
        *(uint4*)((char*)Bl + byte) = v;
    }
    __syncthreads();

    int wid = t >> 6, lane = t & 63;
    int r0 = wid * 16;
    int lrow = lane & 15, lhi = lane >> 4;
    float4v acc[8];
#pragma unroll
    for (int nf = 0; nf < 8; nf++) acc[nf] = (float4v)(0.f);

#pragma unroll
    for (int c = 0; c < 4; c++) {
        int ra = r0 + lrow;
        int byteA = (ra * 256 + (c * 32 + lhi * 8) * 2) ^ ((ra & 7) << 4);
        short8v a = *(short8v*)((char*)Al + byteA);
#pragma unroll
        for (int nf = 0; nf < 8; nf++) {
            int jb = nf * 16 + lrow;
            int byteB = (jb * 256 + (c * 32 + lhi * 8) * 2) ^ ((jb & 7) << 4);
            short8v b = *(short8v*)((char*)Bl + byteB);
            acc[nf] = __builtin_amdgcn_mfma_f32_16x16x32_bf16(a, b, acc[nf], 0, 0, 0);
        }
    }
    __syncthreads();   // Al/Bl dead; reuse as Cl

    // C/D: col = lane&15, row = (lane>>4)*4 + q
#pragma unroll
    for (int nf = 0; nf < 8; nf++) {
#pragma unroll
        for (int q = 0; q < 4; q++) {
            Cl[(r0 + lhi * 4 + q) * 128 + nf * 16 + lrow] = acc[nf][q];
        }
    }
    __syncthreads();

    // pack pairs -> coalesced uint stores: h2u[(p*NG + g)*128 + cc] = {lo=batch2p, hi=batch2p+1}
#pragma unroll
    for (int s = 0; s < 16; s++) {
        int flat = t + s * 256;           // 0..4095
        int gi = flat >> 7, cc = flat & 127;
        float lo = Cl[gi * 128 + cc];
        float hi = Cl[(32 + gi) * 128 + cc];
        uint u = (uint)f2bf(lo) | ((uint)f2bf(hi) << 16);
        h2u[((size_t)p * NG + g0 + gi) * 128 + cc] = u;
    }
}

// ---------------- fused gather + relu + weighted reduce (pair-interleaved, padded CSR) ----------------
// blockIdx & 3 = batch-pair. Wave owns contiguous nodes; bookkeeping wave-uniform (SGPR);
// row gathers: buffer_load_dwordx2, soffset = SGPR row byte offset, voffset = lane*8.
// 8 gathers in flight. At the random-row per-XCD L2-BW roofline (~90%) — do not touch.
__global__ __launch_bounds__(512)
void k_aggp(const uint* __restrict__ hp, const int2* __restrict__ csr,
            const int* __restrict__ offs, const int* __restrict__ padcnt,
            const float* __restrict__ cval, const float* __restrict__ b1,
            float* __restrict__ s_acc, int N, int npw) {
    int p    = blockIdx.x & 3;
    int wid  = threadIdx.x >> 6, lane = threadIdx.x & 63;
    int w    = __builtin_amdgcn_readfirstlane((blockIdx.x >> 2) * 8 + wid);
    int4v sr = make_srsrc(hp + (size_t)p * NG * 128);    // pair table base
    int voff = lane * 8;                                  // per-lane byte offset
    int l2 = lane * 2;
    float bx = b1[l2], by = b1[l2 + 1];
    float sx0 = 0.f, sx1 = 0.f, sy0 = 0.f, sy1 = 0.f;

    int i0 = w * npw;
    int i1 = min(N, i0 + npw);
    for (int i = i0; i < i1; ++i) {
        int   e  = offs[i];
        int   pc = padcnt[i];
        float cv = cval[i];
        float ax0 = 0.f, ax1 = 0.f, ay0 = 0.f, ay1 = 0.f;
        for (int q = 0; q < pc; q += 8) {
            int ee = e + q;
            int2 c0 = csr[ee],     c1 = csr[ee + 1], c2 = csr[ee + 2], c3 = csr[ee + 3];
            int2 c4 = csr[ee + 4], c5 = csr[ee + 5], c6 = csr[ee + 6], c7 = csr[ee + 7];
            f2v u0 = llvm_rbl_v2f32(sr, voff, c0.x << 9, 0);
            f2v u1 = llvm_rbl_v2f32(sr, voff, c1.x << 9, 0);
            f2v u2 = llvm_rbl_v2f32(sr, voff, c2.x << 9, 0);
            f2v u3 = llvm_rbl_v2f32(sr, voff, c3.x << 9, 0);
            f2v u4 = llvm_rbl_v2f32(sr, voff, c4.x << 9, 0);
            f2v u5 = llvm_rbl_v2f32(sr, voff, c5.x << 9, 0);
            f2v u6 = llvm_rbl_v2f32(sr, voff, c6.x << 9, 0);
            f2v u7 = llvm_rbl_v2f32(sr, voff, c7.x << 9, 0);
            float n0 = __int_as_float(c0.y), n1 = __int_as_float(c1.y);
            float n2 = __int_as_float(c2.y), n3 = __int_as_float(c3.y);
            float n4 = __int_as_float(c4.y), n5 = __int_as_float(c5.y);
            float n6 = __int_as_float(c6.y), n7 = __int_as_float(c7.y);
            uint a, b;
            a = __float_as_uint(u0.x); b = __float_as_uint(u0.y);
            ax0 = fmaf(n0, bf_lo(a), ax0); ax1 = fmaf(n0, bf_hi(a), ax1);
            ay0 = fmaf(n0, bf_lo(b), ay0); ay1 = fmaf(n0, bf_hi(b), ay1);
            a = __float_as_uint(u1.x); b = __float_as_uint(u1.y);
            ax0 = fmaf(n1, bf_lo(a), ax0); ax1 = fmaf(n1, bf_hi(a), ax1);
            ay0 = fmaf(n1, bf_lo(b), ay0); ay1 = fmaf(n1, bf_hi(b), ay1);
            a = __float_as_uint(u2.x); b = __float_as_uint(u2.y);
            ax0 = fmaf(n2, bf_lo(a), ax0); ax1 = fmaf(n2, bf_hi(a), ax1);
            ay0 = fmaf(n2, bf_lo(b), ay0); ay1 = fmaf(n2, bf_hi(b), ay1);
            a = __float_as_uint(u3.x); b = __float_as_uint(u3.y);
            ax0 = fmaf(n3, bf_lo(a), ax0); ax1 = fmaf(n3, bf_hi(a), ax1);
            ay0 = fmaf(n3, bf_lo(b), ay0); ay1 = fmaf(n3, bf_hi(b), ay1);
            a = __float_as_uint(u4.x); b = __float_as_uint(u4.y);
            ax0 = fmaf(n4, bf_lo(a), ax0); ax1 = fmaf(n4, bf_hi(a), ax1);
            ay0 = fmaf(n4, bf_lo(b), ay0); ay1 = fmaf(n4, bf_hi(b), ay1);
            a = __float_as_uint(u5.x); b = __float_as_uint(u5.y);
            ax0 = fmaf(n5, bf_lo(a), ax0); ax1 = fmaf(n5, bf_hi(a), ax1);
            ay0 = fmaf(n5, bf_lo(b), ay0); ay1 = fmaf(n5, bf_hi(b), ay1);
            a = __float_as_uint(u6.x); b = __float_as_uint(u6.y);
            ax0 = fmaf(n6, bf_lo(a), ax0); ax1 = fmaf(n6, bf_hi(a), ax1);
            ay0 = fmaf(n6, bf_lo(b), ay0); ay1 = fmaf(n6, bf_hi(b), ay1);
            a = __float_as_uint(u7.x); b = __float_as_uint(u7.y);
            ax0 = fmaf(n7, bf_lo(a), ax0); ax1 = fmaf(n7, bf_hi(a), ax1);
            ay0 = fmaf(n7, bf_lo(b), ay0); ay1 = fmaf(n7, bf_hi(b), ay1);
        }
        sx0 += cv * fmaxf(ax0 + bx, 0.f);
        sx1 += cv * fmaxf(ax1 + bx, 0.f);
        sy0 += cv * fmaxf(ay0 + by, 0.f);
        sy1 += cv * fmaxf(ay1 + by, 0.f);
    }

    // block reduce: 8 waves -> 256 sums (2 batches x 128 feats) -> 1 atomic each
    __shared__ float red[8][256];
    red[wid][lane * 4 + 0] = sx0;
    red[wid][lane * 4 + 1] = sx1;
    red[wid][lane * 4 + 2] = sy0;
    red[wid][lane * 4 + 3] = sy1;
    __syncthreads();
    int t = threadIdx.x;
    if (t < 256) {
        float s = 0.f;
#pragma unroll
        for (int wv = 0; wv < 8; wv++) s += red[wv][t];
        int l = t >> 2, c = t & 3;
        atomicAdd(&s_acc[(2 * p + (c & 1)) * 128 + 2 * l + (c >> 1)], s);
    }
}

// out[b][j] = (s[b] @ W2)[j] / N + b2[j]   (tiny: 8x128x128)
__global__ void k_final(const float* __restrict__ s_acc, const float* __restrict__ W2,
                        const float* __restrict__ b2, float* __restrict__ out, float invN) {
    __shared__ float ss[1024];
    int t = threadIdx.x;  // 128 threads
    for (int idx = t; idx < 1024; idx += 128) ss[idx] = s_acc[idx];
    __syncthreads();
    float acc[8];
#pragma unroll
    for (int b = 0; b < 8; b++) acc[b] = 0.f;
    for (int k = 0; k < 128; k++) {
        float w = W2[k * 128 + t];
#pragma unroll
        for (int b = 0; b < 8; b++) acc[b] += ss[b * 128 + k] * w;
    }
    float bb = b2[t];
#pragma unroll
    for (int b = 0; b < 8; b++) out[b * 128 + t] = acc[b] * invN + bb;
}

// ---------------- launcher ----------------

extern "C" void kernel_launch(void* const* d_in, const int* in_sizes, int n_in,
                              void* d_out, int out_size, void* d_ws, size_t ws_size,
                              hipStream_t stream) {
    const float* gene = (const float*)d_in[0];
    const float* W1   = (const float*)d_in[1];
    const float* b1   = (const float*)d_in[2];
    const float* W2   = (const float*)d_in[3];
    const float* b2   = (const float*)d_in[4];
    const int*   gid  = (const int*)d_in[5];
    const int*   eidx = (const int*)d_in[6];
    int N = in_sizes[5];
    int E = in_sizes[6] / 2;
    const int* src = eidx;
    const int* dst = eidx + E;
    float* out = (float*)d_out;

    char* p = (char*)d_ws;
    auto alloc = [&](size_t bytes) -> char* {
        char* r = p; p += (bytes + 255) & ~(size_t)255; return r;
    };
    size_t csr_cap = (size_t)E + 8 * (size_t)N;          // padded upper bound (entries)
    int*   ideg   = (int*)  alloc((size_t)N * 4);
    float* dinv   = (float*)alloc((size_t)N * 4);
    float* cval   = (float*)alloc((size_t)N * 4);
    float* wself  = (float*)alloc((size_t)N * 4);
    int*   padcnt = (int*)  alloc((size_t)N * 4);
    int*   offs   = (int*)  alloc((size_t)N * 4);
    int*   cursor = (int*)  alloc((size_t)N * 4);
    int*   bsums  = (int*)  alloc(256 * 4);
    int2*  csr    = (int2*) alloc(csr_cap * 8);
    float* s_acc  = (float*)alloc(1024 * 4);
    uint*  h2     = (uint*) alloc((size_t)NG * BB * FD * 2);   // 41 MB, bf16 [pair][g][f][2]
    ushort* w1t   = (ushort*)alloc(128 * 128 * 2);             // bf16 W1^T [j][k]

    int nb = (N + 255) / 256;   // 196 (must be <= 256 for scan2)
    int eb = (E + 255) / 256;
    int zn4 = (int)(csr_cap * 8 / 16);                   // int4 count to zero
    int zb  = (zn4 + 255) / 256;
    int hblk = 4 * (NG / 32);                            // 2500 h-tiles

    const int NBLK = 2048;                 // 512 blocks/pair * 8 waves = 4096 waves per pair
    int wavesPerPair = (NBLK / 4) * 8;
    int npw = (N + wavesPerPair - 1) / wavesPerPair;     // contiguous nodes per wave

    k_setup<<<zb, 256, 0, stream>>>((int4*)csr, zn4, ideg, s_acc, W1, w1t, N);
    k_count<<<eb, 256, 0, stream>>>(dst, ideg, E);
    k_scanA<<<nb, 256, 0, stream>>>(ideg, dinv, cval, wself, padcnt, offs, bsums, N);
    k_scan2<<<1, 256, 0, stream>>>(bsums, nb);
    k_scanB<<<nb, 256, 0, stream>>>(offs, bsums, gid, wself, cursor, csr, N);
    k_fillh<<<eb + hblk, 256, 0, stream>>>(src, dst, gid, dinv, cval, offs, cursor,
                                           csr, E, eb, gene, w1t, h2);
    k_aggp <<<NBLK, 512, 0, stream>>>(h2, csr, offs, padcnt,
                                      cval, b1, s_acc, N, npw);
    k_final<<<1, 128, 0, stream>>>(s_acc, W2, b2, out, 1.0f / (float)N);
}